// Round 1
// baseline (10221.974 us; speedup 1.0000x reference)
//
#include <hip/hip_runtime.h>
#include <math.h>

#define Bq 2
#define Tq 512
#define Cq 512
#define Hq 8
#define Lq 12
#define Vq 2560
#define F4q 2048
#define BTq (Bq*Tq)

typedef float4 f4;

static __device__ __forceinline__ float sigm(float x){ return 1.0f/(1.0f+expf(-x)); }
static __device__ __forceinline__ float splus(float x){ return fmaxf(x,0.0f) + log1pf(expf(-fabsf(x))); }

// ---------------- embedding gather ----------------
__global__ __launch_bounds__(128) void k_embed(const int* __restrict__ tok,
    const float* __restrict__ emb, float* __restrict__ x){
  int bt = blockIdx.x;
  int id = tok[bt];
  ((f4*)(x + (size_t)bt*Cq))[threadIdx.x] = ((const f4*)(emb + (size_t)id*Cq))[threadIdx.x];
}

// ---------------- layernorm over C=512 (block=128, f4 per thread) ----------------
__global__ __launch_bounds__(128) void k_ln(const float* __restrict__ x, const float* __restrict__ w,
    const float* __restrict__ b, float* __restrict__ o, float eps){
  int bt = blockIdx.x, tid = threadIdx.x;
  f4 v = ((const f4*)(x + (size_t)bt*Cq))[tid];
  float s = v.x+v.y+v.z+v.w;
  float q = v.x*v.x + v.y*v.y + v.z*v.z + v.w*v.w;
  #pragma unroll
  for (int m=1;m<64;m<<=1){ s += __shfl_xor(s,m); q += __shfl_xor(q,m); }
  __shared__ float ss[2], qs[2];
  if ((tid&63)==0){ ss[tid>>6]=s; qs[tid>>6]=q; }
  __syncthreads();
  s = ss[0]+ss[1]; q = qs[0]+qs[1];
  float mean = s*(1.0f/Cq);
  float inv = rsqrtf(q*(1.0f/Cq) - mean*mean + eps);
  f4 W = ((const f4*)w)[tid], Bb = ((const f4*)b)[tid];
  f4 r;
  r.x = (v.x-mean)*inv*W.x + Bb.x;
  r.y = (v.y-mean)*inv*W.y + Bb.y;
  r.z = (v.z-mean)*inv*W.z + Bb.z;
  r.w = (v.w-mean)*inv*W.w + Bb.w;
  ((f4*)(o + (size_t)bt*Cq))[tid] = r;
}

// ---------------- time-shift mixes: 6 outputs ----------------
__global__ __launch_bounds__(128) void k_mix(const float* __restrict__ h,
    const float* __restrict__ mr, const float* __restrict__ mw, const float* __restrict__ mk,
    const float* __restrict__ mv, const float* __restrict__ ma, const float* __restrict__ mg,
    float* __restrict__ xr, float* __restrict__ xw, float* __restrict__ xk,
    float* __restrict__ xv, float* __restrict__ xa, float* __restrict__ xg){
  int bt = blockIdx.x, tid = threadIdx.x;
  int t = bt & (Tq-1);
  f4 hc = ((const f4*)(h + (size_t)bt*Cq))[tid];
  f4 hp = make_float4(0.f,0.f,0.f,0.f);
  if (t) hp = ((const f4*)(h + (size_t)(bt-1)*Cq))[tid];
  f4 xx; xx.x = hp.x-hc.x; xx.y = hp.y-hc.y; xx.z = hp.z-hc.z; xx.w = hp.w-hc.w;
  #define MIXOUT(dst, m) { f4 M = ((const f4*)(m))[tid]; f4 r; \
    r.x = fmaf(xx.x, M.x, hc.x); r.y = fmaf(xx.y, M.y, hc.y); \
    r.z = fmaf(xx.z, M.z, hc.z); r.w = fmaf(xx.w, M.w, hc.w); \
    ((f4*)((dst) + (size_t)bt*Cq))[tid] = r; }
  MIXOUT(xr, mr) MIXOUT(xw, mw) MIXOUT(xk, mk)
  MIXOUT(xv, mv) MIXOUT(xa, ma) MIXOUT(xg, mg)
  #undef MIXOUT
}

// ---------------- fp32 tiled GEMM: C[M,N] = act(A[M,K] @ B[K,N]) (+bias) (+accum) ----
// tile 32x64, 128 threads, 4x4 per thread, TK=16
template<int ACT, bool ACCUM, bool BIAS>
__global__ __launch_bounds__(128) void k_gemm(const float* __restrict__ A,
    const float* __restrict__ Bm, const float* __restrict__ bias,
    float* __restrict__ Cm, int M, int N, int K){
  __shared__ __align__(16) float As[16][36];
  __shared__ __align__(16) float Bs[16][68];
  const int tid = threadIdx.x;
  const int tn = tid & 15, tm = tid >> 4;
  const int row0 = blockIdx.y << 5, n0 = blockIdx.x << 6;
  const int arow = tid >> 2, acol = (tid & 3) << 2;
  const int brow = tid >> 3, bcol = (tid & 7) << 3;
  float acc[4][4] = {};
  const float* aptr = A + (size_t)(row0 + arow)*K + acol;
  const float* bptr = Bm + (size_t)brow*N + n0 + bcol;
  const bool bok = (n0 + bcol) < N;
  for (int k0=0;k0<K;k0+=16){
    f4 a4 = *(const f4*)(aptr + k0);
    f4 b0 = make_float4(0.f,0.f,0.f,0.f), b1 = b0;
    if (bok){
      const float* bp = bptr + (size_t)k0*N;
      b0 = *(const f4*)bp; b1 = *(const f4*)(bp+4);
    }
    __syncthreads();
    As[acol+0][arow]=a4.x; As[acol+1][arow]=a4.y; As[acol+2][arow]=a4.z; As[acol+3][arow]=a4.w;
    *(f4*)&Bs[brow][bcol]   = b0;
    *(f4*)&Bs[brow][bcol+4] = b1;
    __syncthreads();
    #pragma unroll
    for (int k=0;k<16;k++){
      f4 a  = *(const f4*)&As[k][tm<<2];
      f4 bq = *(const f4*)&Bs[k][tn<<2];
      float ar[4] = {a.x,a.y,a.z,a.w};
      float br[4] = {bq.x,bq.y,bq.z,bq.w};
      #pragma unroll
      for (int ii=0;ii<4;ii++)
        #pragma unroll
        for (int jj=0;jj<4;jj++)
          acc[ii][jj] = fmaf(ar[ii], br[jj], acc[ii][jj]);
    }
  }
  #pragma unroll
  for (int ii=0;ii<4;ii++){
    int row = row0 + (tm<<2) + ii;
    #pragma unroll
    for (int jj=0;jj<4;jj++){
      int col = n0 + (tn<<2) + jj;
      if (col < N){
        float v = acc[ii][jj];
        if (ACT==1) v = tanhf(v);
        else if (ACT==2) v = sigm(v);
        else if (ACT==3){ v = fmaxf(v, 0.0f); v = v*v; }
        if (BIAS) v += bias[col];
        size_t o = (size_t)row*N + col;
        if (ACCUM) Cm[o] += v; else Cm[o] = v;
      }
    }
  }
}

// ---------------- pre-scan elementwise: build scan inputs ----------------
// scan_in layout: [B*H][T][6][64] strips: 0=r 1=wdec 2=k2 3=v 4=-kk 5=kk*a
__global__ __launch_bounds__(64) void k_prescan(int layer,
    const float* __restrict__ rb, const float* __restrict__ kb,
    const float* __restrict__ vraw, const float* __restrict__ vfirst,
    const float* __restrict__ wpp, const float* __restrict__ aap, const float* __restrict__ vvp,
    const float* __restrict__ w0, const float* __restrict__ a0, const float* __restrict__ v0,
    const float* __restrict__ kkw, const float* __restrict__ kaw,
    float* __restrict__ scan_in, float* __restrict__ k2b, float* __restrict__ vb){
  int bt = blockIdx.x, hh = blockIdx.y, n = threadIdx.x;
  int c = (hh<<6) + n;
  size_t ic = (size_t)bt*Cq + c;
  int b = bt >> 9, t = bt & (Tq-1);
  float kvv = kb[ic];
  float kkq = kvv * kkw[c];
  float s = kkq*kkq;
  #pragma unroll
  for (int m=1;m<64;m<<=1) s += __shfl_xor(s,m);
  float kkn = kkq / fmaxf(sqrtf(s), 1e-12f);
  float aq = sigm(a0[c] + aap[ic]);
  float wvv = -splus(-(w0[c] + wpp[ic])) - 0.5f;
  float wd = expf(-expf(wvv));
  float vq;
  if (layer==0) vq = vfirst[ic];
  else { float vr = vraw[ic]; vq = fmaf(sigm(v0[c]+vvp[ic]), vfirst[ic]-vr, vr); }
  float k2q = kvv * fmaf(aq-1.0f, kaw[c], 1.0f);
  float* dst = scan_in + ((size_t)(b*Hq+hh)*Tq + t)*384;
  dst[n]       = rb[ic];
  dst[64+n]    = wd;
  dst[128+n]   = k2q;
  dst[192+n]   = vq;
  dst[256+n]   = -kkn;
  dst[320+n]   = kkn*aq;
  k2b[ic] = k2q;
  vb[ic]  = vq;
}

// ---------------- sequential RWKV-7 state scan ----------------
// grid = B*H blocks, 256 threads: thread (i = tid>>2) owns state row i, (tid&3) owns a 16-col chunk.
__global__ __launch_bounds__(256) void k_scan(const float* __restrict__ scan_in, float* __restrict__ y){
  __shared__ __align__(16) float stage[2][384];
  int bh = blockIdx.x;
  int b = bh >> 3, hh = bh & 7;
  int tid = threadIdx.x;
  int i = tid >> 2, cqd = tid & 3, jc = cqd << 4;
  const float* base = scan_in + (size_t)bh*Tq*384;
  if (tid < 96) ((f4*)stage[0])[tid] = ((const f4*)base)[tid];
  float S[16];
  #pragma unroll
  for (int u=0;u<16;u++) S[u]=0.0f;
  float* yrow = y + (size_t)b*Tq*Cq + (hh<<6) + i;
  __syncthreads();
  for (int t=0;t<Tq;t++){
    const float* st = stage[t&1];
    f4 pf;
    bool has = (tid<96) && (t+1<Tq);
    if (has) pf = ((const f4*)(base + (size_t)(t+1)*384))[tid];
    float rv[16], wv[16], kv[16], av[16], bv[16];
    #pragma unroll
    for (int qd=0;qd<4;qd++){
      *(f4*)&rv[4*qd] = *(const f4*)(st +       jc + 4*qd);
      *(f4*)&wv[4*qd] = *(const f4*)(st +  64 + jc + 4*qd);
      *(f4*)&kv[4*qd] = *(const f4*)(st + 128 + jc + 4*qd);
      *(f4*)&av[4*qd] = *(const f4*)(st + 256 + jc + 4*qd);
      *(f4*)&bv[4*qd] = *(const f4*)(st + 320 + jc + 4*qd);
    }
    float vi = st[192 + i];
    float sa0=0.f,sa1=0.f,sa2=0.f,sa3=0.f;
    #pragma unroll
    for (int u=0;u<4;u++){
      sa0 = fmaf(S[u],    av[u],    sa0);
      sa1 = fmaf(S[u+4],  av[u+4],  sa1);
      sa2 = fmaf(S[u+8],  av[u+8],  sa2);
      sa3 = fmaf(S[u+12], av[u+12], sa3);
    }
    float sa = (sa0+sa1)+(sa2+sa3);
    sa += __shfl_xor(sa,1);
    sa += __shfl_xor(sa,2);
    #pragma unroll
    for (int u=0;u<16;u++)
      S[u] = fmaf(vi, kv[u], fmaf(sa, bv[u], S[u]*wv[u]));
    float o0=0.f,o1=0.f,o2=0.f,o3=0.f;
    #pragma unroll
    for (int u=0;u<4;u++){
      o0 = fmaf(S[u],    rv[u],    o0);
      o1 = fmaf(S[u+4],  rv[u+4],  o1);
      o2 = fmaf(S[u+8],  rv[u+8],  o2);
      o3 = fmaf(S[u+12], rv[u+12], o3);
    }
    float o = (o0+o1)+(o2+o3);
    o += __shfl_xor(o,1);
    o += __shfl_xor(o,2);
    if (cqd==0) yrow[(size_t)t*Cq] = o;
    if (has) ((f4*)stage[(t&1)^1])[tid] = pf;
    __syncthreads();
  }
}

// ---------------- post-scan: groupnorm + bonus term + gate ----------------
__global__ __launch_bounds__(512) void k_post(const float* __restrict__ y,
    const float* __restrict__ rb, const float* __restrict__ k2b,
    const float* __restrict__ vb, const float* __restrict__ gb,
    const float* __restrict__ gnw, const float* __restrict__ gnb,
    const float* __restrict__ rk, float* __restrict__ z){
  int bt = blockIdx.x, c = threadIdx.x;
  size_t ic = (size_t)bt*Cq + c;
  float yv = y[ic];
  float s = yv, q = yv*yv;
  float rr = rb[ic]*k2b[ic]*rk[c];
  #pragma unroll
  for (int m=1;m<64;m<<=1){ s += __shfl_xor(s,m); q += __shfl_xor(q,m); rr += __shfl_xor(rr,m); }
  float mean = s*(1.0f/64.0f);
  float inv = rsqrtf(q*(1.0f/64.0f) - mean*mean + 64e-5f);
  float gn = (yv-mean)*inv*gnw[c] + gnb[c];
  z[ic] = (gn + rr*vb[ic]) * gb[ic];
}

extern "C" void kernel_launch(void* const* d_in, const int* in_sizes, int n_in,
                              void* d_out, int out_size, void* d_ws, size_t ws_size,
                              hipStream_t stream){
  const int*   tok  = (const int*)d_in[0];
  const float* emb  = (const float*)d_in[1];
  const float* ln1w = (const float*)d_in[2];
  const float* ln1b = (const float*)d_in[3];
  const float* mxr  = (const float*)d_in[4];
  const float* mxw  = (const float*)d_in[5];
  const float* mxk  = (const float*)d_in[6];
  const float* mxv  = (const float*)d_in[7];
  const float* mxa  = (const float*)d_in[8];
  const float* mxg  = (const float*)d_in[9];
  const float* w0   = (const float*)d_in[10];
  const float* w1   = (const float*)d_in[11];
  const float* w2   = (const float*)d_in[12];
  const float* a0   = (const float*)d_in[13];
  const float* a1   = (const float*)d_in[14];
  const float* a2   = (const float*)d_in[15];
  const float* v0   = (const float*)d_in[16];
  const float* v1   = (const float*)d_in[17];
  const float* v2   = (const float*)d_in[18];
  const float* g1   = (const float*)d_in[19];
  const float* g2   = (const float*)d_in[20];
  const float* kkw  = (const float*)d_in[21];
  const float* kaw  = (const float*)d_in[22];
  const float* rkw  = (const float*)d_in[23];
  const float* Wr   = (const float*)d_in[24];
  const float* Wk   = (const float*)d_in[25];
  const float* Wv   = (const float*)d_in[26];
  const float* Wo   = (const float*)d_in[27];
  const float* gnw  = (const float*)d_in[28];
  const float* gnb  = (const float*)d_in[29];
  const float* ln2w = (const float*)d_in[30];
  const float* ln2b = (const float*)d_in[31];
  const float* Wfk  = (const float*)d_in[32];
  const float* Wfv  = (const float*)d_in[33];
  const float* lnow = (const float*)d_in[34];
  const float* lnob = (const float*)d_in[35];
  const float* Whead= (const float*)d_in[36];
  const float* bhead= (const float*)d_in[37];
  float* out = (float*)d_out;

  float* ws = (float*)d_ws;
  size_t off = 0;
  const size_t BTC = (size_t)BTq*Cq;
  float* x      = ws + off; off += BTC;
  float* h      = ws + off; off += BTC;
  float* xr     = ws + off; off += BTC;
  float* xw     = ws + off; off += BTC;
  float* xk     = ws + off; off += BTC;
  float* xv     = ws + off; off += BTC;
  float* xa     = ws + off; off += BTC;
  float* xg     = ws + off; off += BTC;
  float* rb     = ws + off; off += BTC;
  float* kb     = ws + off; off += BTC;
  float* vraw   = ws + off; off += BTC;
  float* vfirst = ws + off; off += BTC;
  float* wpp    = ws + off; off += BTC;
  float* aap    = ws + off; off += BTC;
  float* vvp    = ws + off; off += BTC;
  float* gbuf   = ws + off; off += BTC;
  float* k2b    = ws + off; off += BTC;
  float* vbuf   = ws + off; off += BTC;
  float* yb     = ws + off; off += BTC;
  float* t1     = ws + off; off += (size_t)BTq*64;
  float* t2     = ws + off; off += (size_t)BTq*64;
  float* t3     = ws + off; off += (size_t)BTq*32;
  float* t4     = ws + off; off += (size_t)BTq*128;
  float* scan_in= ws + off; off += (size_t)Bq*Hq*Tq*384;
  float* fk     = ws + off; off += (size_t)BTq*F4q;
  float* zb     = xr;  // alias: xr is dead after the Wr GEMM, reused for gated output

  dim3 gN512(Cq/64,  BTq/32);
  dim3 gN64 (1,      BTq/32);
  dim3 gN32 (1,      BTq/32);
  dim3 gN128(2,      BTq/32);
  dim3 gFFN (F4q/64, BTq/32);
  dim3 gHead(Vq/64,  BTq/32);

  k_embed<<<BTq,128,0,stream>>>(tok, emb, x);
  for (int l=0;l<Lq;l++){
    size_t lc = (size_t)l*Cq;
    k_ln<<<BTq,128,0,stream>>>(x, ln1w+lc, ln1b+lc, h, 1e-5f);
    k_mix<<<BTq,128,0,stream>>>(h, mxr+lc, mxw+lc, mxk+lc, mxv+lc, mxa+lc, mxg+lc,
                                xr, xw, xk, xv, xa, xg);
    k_gemm<0,false,false><<<gN512,128,0,stream>>>(xr, Wr + (size_t)l*Cq*Cq, nullptr, rb, BTq, Cq, Cq);
    k_gemm<0,false,false><<<gN512,128,0,stream>>>(xk, Wk + (size_t)l*Cq*Cq, nullptr, kb, BTq, Cq, Cq);
    k_gemm<0,false,false><<<gN512,128,0,stream>>>(xv, Wv + (size_t)l*Cq*Cq, nullptr,
                                                  (l==0 ? vfirst : vraw), BTq, Cq, Cq);
    k_gemm<1,false,false><<<gN64,128,0,stream>>>(xw, w1 + (size_t)l*Cq*64, nullptr, t1, BTq, 64, Cq);
    k_gemm<0,false,false><<<gN512,128,0,stream>>>(t1, w2 + (size_t)l*64*Cq, nullptr, wpp, BTq, Cq, 64);
    k_gemm<0,false,false><<<gN64,128,0,stream>>>(xa, a1 + (size_t)l*Cq*64, nullptr, t2, BTq, 64, Cq);
    k_gemm<0,false,false><<<gN512,128,0,stream>>>(t2, a2 + (size_t)l*64*Cq, nullptr, aap, BTq, Cq, 64);
    if (l > 0){
      k_gemm<0,false,false><<<gN32,128,0,stream>>>(xv, v1 + (size_t)l*Cq*32, nullptr, t3, BTq, 32, Cq);
      k_gemm<0,false,false><<<gN512,128,0,stream>>>(t3, v2 + (size_t)l*32*Cq, nullptr, vvp, BTq, Cq, 32);
    }
    k_gemm<2,false,false><<<gN128,128,0,stream>>>(xg, g1 + (size_t)l*Cq*128, nullptr, t4, BTq, 128, Cq);
    k_gemm<0,false,false><<<gN512,128,0,stream>>>(t4, g2 + (size_t)l*128*Cq, nullptr, gbuf, BTq, Cq, 128);
    k_prescan<<<dim3(BTq,Hq),64,0,stream>>>(l, rb, kb, vraw, vfirst, wpp, aap, vvp,
                                            w0+lc, a0+lc, v0+lc, kkw+lc, kaw+lc,
                                            scan_in, k2b, vbuf);
    k_scan<<<Bq*Hq,256,0,stream>>>(scan_in, yb);
    k_post<<<BTq,512,0,stream>>>(yb, rb, k2b, vbuf, gbuf, gnw+lc, gnb+lc, rkw+lc, zb);
    k_gemm<0,true,false><<<gN512,128,0,stream>>>(zb, Wo + (size_t)l*Cq*Cq, nullptr, x, BTq, Cq, Cq);
    k_ln<<<BTq,128,0,stream>>>(x, ln2w+lc, ln2b+lc, h, 1e-5f);
    k_gemm<3,false,false><<<gFFN,128,0,stream>>>(h, Wfk + (size_t)l*Cq*F4q, nullptr, fk, BTq, F4q, Cq);
    k_gemm<0,true,false><<<gN512,128,0,stream>>>(fk, Wfv + (size_t)l*F4q*Cq, nullptr, x, BTq, Cq, F4q);
  }
  k_ln<<<BTq,128,0,stream>>>(x, lnow, lnob, h, 1e-5f);
  k_gemm<0,false,true><<<gHead,128,0,stream>>>(h, Whead, bhead, out, BTq, Vq, Cq);
}

// Round 6
// 4625.088 us; speedup vs baseline: 2.2101x; 2.2101x over previous
//
#include <hip/hip_runtime.h>
#include <hip/hip_bf16.h>
#include <math.h>

#define Bq 2
#define Tq 512
#define Cq 512
#define Hq 8
#define Lq 12
#define Vq 2560
#define F4q 2048
#define BTq (Bq*Tq)

typedef float4 f4;
typedef __hip_bfloat16 bf16;
typedef __attribute__((ext_vector_type(8))) short bf16x8;
typedef __attribute__((ext_vector_type(4))) float f32x4;

static __device__ __forceinline__ float sigm(float x){ return 1.0f/(1.0f+expf(-x)); }
static __device__ __forceinline__ float splus(float x){ return fmaxf(x,0.0f) + log1pf(expf(-fabsf(x))); }
static __device__ __forceinline__ float b2f(short u){ unsigned int x = ((unsigned int)(unsigned short)u)<<16; float f; __builtin_memcpy(&f,&x,4); return f; }
static __device__ __forceinline__ short f2b(float f){ bf16 h = __float2bfloat16(f); unsigned short us; __builtin_memcpy(&us,&h,2); return (short)us; }

__device__ __forceinline__ void gload16(const void* gptr, void* lptr){
  __builtin_amdgcn_global_load_lds(
    (const __attribute__((address_space(1))) void*)gptr,
    (__attribute__((address_space(3))) void*)lptr, 16, 0, 0);
}

__global__ __launch_bounds__(128) void k_embed(const int* __restrict__ tok,
    const float* __restrict__ emb, float* __restrict__ x){
  int bt = blockIdx.x;
  int id = tok[bt];
  ((f4*)(x + (size_t)bt*Cq))[threadIdx.x] = ((const f4*)(emb + (size_t)id*Cq))[threadIdx.x];
}

// transpose+convert fp32 [K][N] -> bf16 [N][K] (plain, head only)
__global__ __launch_bounds__(256) void k_tr(const float* __restrict__ src, bf16* __restrict__ dst,
    int K, int N, size_t sstride, size_t dstride){
  __shared__ float tile[32][33];
  int l = blockIdx.z;
  const float* s = src + (size_t)l*sstride;
  bf16* d = dst + (size_t)l*dstride;
  int n0 = blockIdx.x*32, k0 = blockIdx.y*32;
  int tx = threadIdx.x, ty = threadIdx.y;
  #pragma unroll
  for (int r=0;r<32;r+=8) tile[ty+r][tx] = s[(size_t)(k0+ty+r)*N + n0+tx];
  __syncthreads();
  #pragma unroll
  for (int r=0;r<32;r+=8) d[(size_t)(n0+ty+r)*K + k0+tx] = __float2bfloat16(tile[tx][ty+r]);
}

// transpose+convert with hi/lo split: fp32 [K][N] -> bf16 [N][K] x2
__global__ __launch_bounds__(256) void k_tr_split(const float* __restrict__ src,
    bf16* __restrict__ dhi, bf16* __restrict__ dlo,
    int K, int N, size_t sstride, size_t dstride){
  __shared__ float tile[32][33];
  int l = blockIdx.z;
  const float* s = src + (size_t)l*sstride;
  int n0 = blockIdx.x*32, k0 = blockIdx.y*32;
  int tx = threadIdx.x, ty = threadIdx.y;
  #pragma unroll
  for (int r=0;r<32;r+=8) tile[ty+r][tx] = s[(size_t)(k0+ty+r)*N + n0+tx];
  __syncthreads();
  #pragma unroll
  for (int r=0;r<32;r+=8){
    float v = tile[tx][ty+r];
    bf16 hv = __float2bfloat16(v);
    size_t idx = (size_t)l*dstride + (size_t)(n0+ty+r)*K + k0+tx;
    dhi[idx] = hv;
    dlo[idx] = __float2bfloat16(v - __bfloat162float(hv));
  }
}

// layernorm fp32 -> fp32
__global__ __launch_bounds__(128) void k_ln(const float* __restrict__ x, const float* __restrict__ w,
    const float* __restrict__ b, float* __restrict__ o){
  int bt = blockIdx.x, tid = threadIdx.x;
  f4 v = ((const f4*)(x + (size_t)bt*Cq))[tid];
  float s = v.x+v.y+v.z+v.w;
  float q = v.x*v.x + v.y*v.y + v.z*v.z + v.w*v.w;
  #pragma unroll
  for (int m=1;m<64;m<<=1){ s += __shfl_xor(s,m); q += __shfl_xor(q,m); }
  __shared__ float ss[2], qs[2];
  if ((tid&63)==0){ ss[tid>>6]=s; qs[tid>>6]=q; }
  __syncthreads();
  s = ss[0]+ss[1]; q = qs[0]+qs[1];
  float mean = s*(1.0f/Cq);
  float inv = rsqrtf(q*(1.0f/Cq) - mean*mean + 1e-5f);
  f4 W = ((const f4*)w)[tid], Bb = ((const f4*)b)[tid];
  f4 r;
  r.x = (v.x-mean)*inv*W.x + Bb.x;
  r.y = (v.y-mean)*inv*W.y + Bb.y;
  r.z = (v.z-mean)*inv*W.z + Bb.z;
  r.w = (v.w-mean)*inv*W.w + Bb.w;
  ((f4*)(o + (size_t)bt*Cq))[tid] = r;
}

// layernorm fp32 -> split bf16 hi/lo
__global__ __launch_bounds__(128) void k_ln_split(const float* __restrict__ x, const float* __restrict__ w,
    const float* __restrict__ b, bf16* __restrict__ oh, bf16* __restrict__ ol){
  int bt = blockIdx.x, tid = threadIdx.x;
  f4 v = ((const f4*)(x + (size_t)bt*Cq))[tid];
  float s = v.x+v.y+v.z+v.w;
  float q = v.x*v.x + v.y*v.y + v.z*v.z + v.w*v.w;
  #pragma unroll
  for (int m=1;m<64;m<<=1){ s += __shfl_xor(s,m); q += __shfl_xor(q,m); }
  __shared__ float ss[2], qs[2];
  if ((tid&63)==0){ ss[tid>>6]=s; qs[tid>>6]=q; }
  __syncthreads();
  s = ss[0]+ss[1]; q = qs[0]+qs[1];
  float mean = s*(1.0f/Cq);
  float inv = rsqrtf(q*(1.0f/Cq) - mean*mean + 1e-5f);
  f4 W = ((const f4*)w)[tid], Bb = ((const f4*)b)[tid];
  float vv[4] = {(v.x-mean)*inv*W.x + Bb.x, (v.y-mean)*inv*W.y + Bb.y,
                 (v.z-mean)*inv*W.z + Bb.z, (v.w-mean)*inv*W.w + Bb.w};
  short4 hi, lo;
  short* hp = &hi.x; short* lp = &lo.x;
  #pragma unroll
  for (int u=0;u<4;u++){ hp[u] = f2b(vv[u]); lp[u] = f2b(vv[u] - b2f(hp[u])); }
  ((short4*)(oh + (size_t)bt*Cq))[tid] = hi;
  ((short4*)(ol + (size_t)bt*Cq))[tid] = lo;
}

// layernorm fp32 -> single bf16 (final, pre-head)
__global__ __launch_bounds__(128) void k_ln_bf(const float* __restrict__ x, const float* __restrict__ w,
    const float* __restrict__ b, bf16* __restrict__ o){
  int bt = blockIdx.x, tid = threadIdx.x;
  f4 v = ((const f4*)(x + (size_t)bt*Cq))[tid];
  float s = v.x+v.y+v.z+v.w;
  float q = v.x*v.x + v.y*v.y + v.z*v.z + v.w*v.w;
  #pragma unroll
  for (int m=1;m<64;m<<=1){ s += __shfl_xor(s,m); q += __shfl_xor(q,m); }
  __shared__ float ss[2], qs[2];
  if ((tid&63)==0){ ss[tid>>6]=s; qs[tid>>6]=q; }
  __syncthreads();
  s = ss[0]+ss[1]; q = qs[0]+qs[1];
  float mean = s*(1.0f/Cq);
  float inv = rsqrtf(q*(1.0f/Cq) - mean*mean + 1e-5f);
  f4 W = ((const f4*)w)[tid], Bb = ((const f4*)b)[tid];
  short4 r;
  r.x = f2b((v.x-mean)*inv*W.x + Bb.x);
  r.y = f2b((v.y-mean)*inv*W.y + Bb.y);
  r.z = f2b((v.z-mean)*inv*W.z + Bb.z);
  r.w = f2b((v.w-mean)*inv*W.w + Bb.w);
  ((short4*)(o + (size_t)bt*Cq))[tid] = r;
}

// time-shift mixes: h fp32 -> six split hi/lo bf16 outputs
__global__ __launch_bounds__(128) void k_mix_split(const float* __restrict__ h,
    const float* __restrict__ mr, const float* __restrict__ mw, const float* __restrict__ mk,
    const float* __restrict__ mv, const float* __restrict__ ma, const float* __restrict__ mg,
    bf16* __restrict__ xrh, bf16* __restrict__ xrl,
    bf16* __restrict__ xwh, bf16* __restrict__ xwl,
    bf16* __restrict__ xkh, bf16* __restrict__ xkl,
    bf16* __restrict__ xvh, bf16* __restrict__ xvl,
    bf16* __restrict__ xah, bf16* __restrict__ xal,
    bf16* __restrict__ xgh, bf16* __restrict__ xgl){
  int bt = blockIdx.x, tid = threadIdx.x;
  int t = bt & (Tq-1);
  f4 hc = ((const f4*)(h + (size_t)bt*Cq))[tid];
  f4 hp = make_float4(0.f,0.f,0.f,0.f);
  if (t) hp = ((const f4*)(h + (size_t)(bt-1)*Cq))[tid];
  float xxx = hp.x-hc.x, xxy = hp.y-hc.y, xxz = hp.z-hc.z, xxw = hp.w-hc.w;
  #define MIXS(dh, dl, m) { f4 M = ((const f4*)(m))[tid]; \
    float m0 = fmaf(xxx, M.x, hc.x), m1 = fmaf(xxy, M.y, hc.y); \
    float m2 = fmaf(xxz, M.z, hc.z), m3 = fmaf(xxw, M.w, hc.w); \
    short4 hi, lo; \
    hi.x = f2b(m0); lo.x = f2b(m0 - b2f(hi.x)); \
    hi.y = f2b(m1); lo.y = f2b(m1 - b2f(hi.y)); \
    hi.z = f2b(m2); lo.z = f2b(m2 - b2f(hi.z)); \
    hi.w = f2b(m3); lo.w = f2b(m3 - b2f(hi.w)); \
    ((short4*)((dh) + (size_t)bt*Cq))[tid] = hi; \
    ((short4*)((dl) + (size_t)bt*Cq))[tid] = lo; }
  MIXS(xrh, xrl, mr) MIXS(xwh, xwl, mw) MIXS(xkh, xkl, mk)
  MIXS(xvh, xvl, mv) MIXS(xah, xal, ma) MIXS(xgh, xgl, mg)
  #undef MIXS
}

// ---------------- split-bf16 3-term MFMA GEMM ----------------
// C[M,N] = act((Ah+Al)[M,K] @ (Bh+Bl)[N,K]^T), noise ~2^-17.
// OM: 0=fp32 store, 1=fp32 accum, 2=split bf16 (Ch hi + Cl lo)
template<int BM,int BN,int BK,int ACT,int OM>
__global__ __launch_bounds__(256) void k_sgemm(
    const bf16* __restrict__ Ah, const bf16* __restrict__ Al,
    const bf16* __restrict__ Bh, const bf16* __restrict__ Bl,
    void* __restrict__ Chv, bf16* __restrict__ Cl, int N, int K){
  constexpr int SWZ = (BK==64)?7:3;
  constexpr int ABYTES = BM*BK*2, BBYTES = BN*BK*2;
  __shared__ __align__(16) char lds[2][2*(ABYTES+BBYTES)];
  const int tid = threadIdx.x;
  const int w = tid>>6, ln = tid&63;
  const int wr = w>>1, wc = w&1;
  constexpr int WM = BM/2, WN = BN/2;
  constexpr int MR = WM/16, NR = WN/16;
  const int row0 = blockIdx.y*BM, col0 = blockIdx.x*BN;
  constexpr int LPR = BK/8;
  constexpr int RPC = 64/LPR;
  constexpr int CHA = BM/RPC, CHB = BN/RPC;
  const int srow = ln/LPR;
  const int kb  = (ln%LPR)*16;

  f32x4 acc[MR][NR];
  #pragma unroll
  for (int m=0;m<MR;m++)
    #pragma unroll
    for (int n=0;n<NR;n++)
      acc[m][n] = (f32x4){0.f,0.f,0.f,0.f};

  auto stage = [&](int buf, int k0){
    #pragma unroll
    for (int q=0;q<CHA/4;q++){
      int ch = w*(CHA/4)+q;
      int row = ch*RPC + srow;
      int kbs = kb ^ ((row&SWZ)<<4);
      size_t go = (size_t)(row0+row)*K + k0;
      gload16((const char*)(Ah+go)+kbs, &lds[buf][ch*1024]);
      gload16((const char*)(Al+go)+kbs, &lds[buf][ABYTES + ch*1024]);
    }
    #pragma unroll
    for (int q=0;q<CHB/4;q++){
      int ch = w*(CHB/4)+q;
      int row = ch*RPC + srow;
      int kbs = kb ^ ((row&SWZ)<<4);
      size_t go = (size_t)(col0+row)*K + k0;
      gload16((const char*)(Bh+go)+kbs, &lds[buf][2*ABYTES + ch*1024]);
      gload16((const char*)(Bl+go)+kbs, &lds[buf][2*ABYTES+BBYTES + ch*1024]);
    }
  };

  stage(0, 0);
  __syncthreads();
  const int nt = K/BK;
  for (int t=0;t<nt;t++){
    int buf = t&1;
    if (t+1<nt) stage(buf^1, (t+1)*BK);
    const char* Lah = &lds[buf][0];
    const char* Lal = &lds[buf][ABYTES];
    const char* Lbh = &lds[buf][2*ABYTES];
    const char* Lbl = &lds[buf][2*ABYTES+BBYTES];
    #pragma unroll
    for (int kk=0;kk<BK/32;kk++){
      bf16x8 ah[MR], al[MR], bh[NR], bl[NR];
      int klo = kk*64 + ((ln>>4)<<4);
      #pragma unroll
      for (int m=0;m<MR;m++){
        int row = wr*WM + m*16 + (ln&15);
        int off = row*(BK*2) + (klo ^ ((row&SWZ)<<4));
        ah[m] = *(const bf16x8*)(Lah + off);
        al[m] = *(const bf16x8*)(Lal + off);
      }
      #pragma unroll
      for (int n=0;n<NR;n++){
        int row = wc*WN + n*16 + (ln&15);
        int off = row*(BK*2) + (klo ^ ((row&SWZ)<<4));
        bh[n] = *(const bf16x8*)(Lbh + off);
        bl[n] = *(const bf16x8*)(Lbl + off);
      }
      #pragma unroll
      for (int m=0;m<MR;m++)
        #pragma unroll
        for (int n=0;n<NR;n++){
          acc[m][n] = __builtin_amdgcn_mfma_f32_16x16x32_bf16(ah[m], bh[n], acc[m][n], 0,0,0);
          acc[m][n] = __builtin_amdgcn_mfma_f32_16x16x32_bf16(ah[m], bl[n], acc[m][n], 0,0,0);
          acc[m][n] = __builtin_amdgcn_mfma_f32_16x16x32_bf16(al[m], bh[n], acc[m][n], 0,0,0);
        }
    }
    __syncthreads();
  }

  #pragma unroll
  for (int m=0;m<MR;m++){
    #pragma unroll
    for (int n=0;n<NR;n++){
      int col = col0 + wc*WN + n*16 + (ln&15);
      int rbase = row0 + wr*WM + m*16 + ((ln>>4)<<2);
      #pragma unroll
      for (int r=0;r<4;r++){
        float v = acc[m][n][r];
        if (ACT==1) v = tanhf(v);
        else if (ACT==2) v = sigm(v);
        else if (ACT==3){ v = fmaxf(v,0.f); v = v*v; }
        size_t o = (size_t)(rbase+r)*N + col;
        if (OM==0) ((float*)Chv)[o] = v;
        else if (OM==1) ((float*)Chv)[o] += v;
        else {
          bf16 hv = __float2bfloat16(v);
          ((bf16*)Chv)[o] = hv;
          Cl[o] = __float2bfloat16(v - __bfloat162float(hv));
        }
      }
    }
  }
}

// plain bf16 MFMA GEMM (head only: post-recurrence, one-shot error)
template<int BM,int BN,int BK>
__global__ __launch_bounds__(256) void k_mgemm(const bf16* __restrict__ A,
    const bf16* __restrict__ Bt, const float* __restrict__ bias,
    float* __restrict__ Cm, int N, int K){
  constexpr int SWZ = (BK==64)?7:3;
  constexpr int ABYTES = BM*BK*2, BBYTES = BN*BK*2;
  __shared__ __align__(16) char lds[2][ABYTES+BBYTES];
  const int tid = threadIdx.x;
  const int w = tid>>6, ln = tid&63;
  const int wr = w>>1, wc = w&1;
  constexpr int WM = BM/2, WN = BN/2;
  constexpr int MR = WM/16, NR = WN/16;
  const int row0 = blockIdx.y*BM, col0 = blockIdx.x*BN;
  constexpr int LPR = BK/8;
  constexpr int RPC = 64/LPR;
  constexpr int CHA = BM/RPC, CHB = BN/RPC;
  const int srow = ln/LPR;
  const int kb  = (ln%LPR)*16;

  f32x4 acc[MR][NR];
  #pragma unroll
  for (int m=0;m<MR;m++)
    #pragma unroll
    for (int n=0;n<NR;n++)
      acc[m][n] = (f32x4){0.f,0.f,0.f,0.f};

  auto stage = [&](int buf, int k0){
    #pragma unroll
    for (int q=0;q<CHA/4;q++){
      int ch = w*(CHA/4)+q;
      int row = ch*RPC + srow;
      int kbs = kb ^ ((row&SWZ)<<4);
      gload16((const char*)(A + (size_t)(row0+row)*K + k0) + kbs, &lds[buf][ch*1024]);
    }
    #pragma unroll
    for (int q=0;q<CHB/4;q++){
      int ch = w*(CHB/4)+q;
      int row = ch*RPC + srow;
      int kbs = kb ^ ((row&SWZ)<<4);
      gload16((const char*)(Bt + (size_t)(col0+row)*K + k0) + kbs, &lds[buf][ABYTES + ch*1024]);
    }
  };

  stage(0, 0);
  __syncthreads();
  const int nt = K/BK;
  for (int t=0;t<nt;t++){
    int buf = t&1;
    if (t+1<nt) stage(buf^1, (t+1)*BK);
    const char* La = &lds[buf][0];
    const char* Lb = &lds[buf][ABYTES];
    #pragma unroll
    for (int kk=0;kk<BK/32;kk++){
      bf16x8 af[MR], bfr[NR];
      int klo = kk*64 + ((ln>>4)<<4);
      #pragma unroll
      for (int m=0;m<MR;m++){
        int row = wr*WM + m*16 + (ln&15);
        af[m] = *(const bf16x8*)(La + row*(BK*2) + (klo ^ ((row&SWZ)<<4)));
      }
      #pragma unroll
      for (int n=0;n<NR;n++){
        int row = wc*WN + n*16 + (ln&15);
        bfr[n] = *(const bf16x8*)(Lb + row*(BK*2) + (klo ^ ((row&SWZ)<<4)));
      }
      #pragma unroll
      for (int m=0;m<MR;m++)
        #pragma unroll
        for (int n=0;n<NR;n++)
          acc[m][n] = __builtin_amdgcn_mfma_f32_16x16x32_bf16(af[m], bfr[n], acc[m][n], 0,0,0);
    }
    __syncthreads();
  }

  #pragma unroll
  for (int m=0;m<MR;m++){
    #pragma unroll
    for (int n=0;n<NR;n++){
      int col = col0 + wc*WN + n*16 + (ln&15);
      int rbase = row0 + wr*WM + m*16 + ((ln>>4)<<2);
      #pragma unroll
      for (int r=0;r<4;r++)
        Cm[(size_t)(rbase+r)*N + col] = acc[m][n][r] + bias[col];
    }
  }
}

__global__ __launch_bounds__(64) void k_prescan(int layer,
    const float* __restrict__ rb, const float* __restrict__ kb,
    const float* __restrict__ vraw, const float* __restrict__ vfirst,
    const float* __restrict__ wpp, const float* __restrict__ aap, const float* __restrict__ vvp,
    const float* __restrict__ w0, const float* __restrict__ a0, const float* __restrict__ v0,
    const float* __restrict__ kkw, const float* __restrict__ kaw,
    float* __restrict__ scan_in, float* __restrict__ k2b, float* __restrict__ vb){
  int bt = blockIdx.x, hh = blockIdx.y, n = threadIdx.x;
  int c = (hh<<6) + n;
  size_t ic = (size_t)bt*Cq + c;
  int b = bt >> 9, t = bt & (Tq-1);
  float kvv = kb[ic];
  float kkq = kvv * kkw[c];
  float s = kkq*kkq;
  #pragma unroll
  for (int m=1;m<64;m<<=1) s += __shfl_xor(s,m);
  float kkn = kkq / fmaxf(sqrtf(s), 1e-12f);
  float aq = sigm(a0[c] + aap[ic]);
  float wvv = -splus(-(w0[c] + wpp[ic])) - 0.5f;
  float wd = expf(-expf(wvv));
  float vq;
  if (layer==0) vq = vfirst[ic];
  else { float vr = vraw[ic]; vq = fmaf(sigm(v0[c]+vvp[ic]), vfirst[ic]-vr, vr); }
  float k2q = kvv * fmaf(aq-1.0f, kaw[c], 1.0f);
  float* dst = scan_in + ((size_t)(b*Hq+hh)*Tq + t)*384;
  dst[n]       = rb[ic];
  dst[64+n]    = wd;
  dst[128+n]   = k2q;
  dst[192+n]   = vq;
  dst[256+n]   = -kkn;
  dst[320+n]   = kkn*aq;
  k2b[ic] = k2q;
  vb[ic]  = vq;
}

struct Step { float r[8], w[8], k[8], a[8], b[8], v; };

__device__ __forceinline__ void load_step(const float* __restrict__ st, int jc, int i, Step& s){
  *(f4*)&s.r[0] = *(const f4*)(st + jc);       *(f4*)&s.r[4] = *(const f4*)(st + jc + 4);
  *(f4*)&s.w[0] = *(const f4*)(st + 64 + jc);  *(f4*)&s.w[4] = *(const f4*)(st + 64 + jc + 4);
  *(f4*)&s.k[0] = *(const f4*)(st + 128 + jc); *(f4*)&s.k[4] = *(const f4*)(st + 128 + jc + 4);
  *(f4*)&s.a[0] = *(const f4*)(st + 256 + jc); *(f4*)&s.a[4] = *(const f4*)(st + 256 + jc + 4);
  *(f4*)&s.b[0] = *(const f4*)(st + 320 + jc); *(f4*)&s.b[4] = *(const f4*)(st + 320 + jc + 4);
  s.v = st[192 + i];
}

__device__ __forceinline__ float step_compute(float S[8], const Step& s){
  float sa0=0.f, sa1=0.f;
  #pragma unroll
  for (int u=0;u<4;u++){ sa0 = fmaf(S[u], s.a[u], sa0); sa1 = fmaf(S[u+4], s.a[u+4], sa1); }
  float sa = sa0+sa1;
  sa += __shfl_xor(sa,1); sa += __shfl_xor(sa,2); sa += __shfl_xor(sa,4);
  #pragma unroll
  for (int u=0;u<8;u++)
    S[u] = fmaf(s.v, s.k[u], fmaf(sa, s.b[u], S[u]*s.w[u]));
  float o0=0.f, o1=0.f;
  #pragma unroll
  for (int u=0;u<4;u++){ o0 = fmaf(S[u], s.r[u], o0); o1 = fmaf(S[u+4], s.r[u+4], o1); }
  float o = o0+o1;
  o += __shfl_xor(o,1); o += __shfl_xor(o,2); o += __shfl_xor(o,4);
  return o;
}

__global__ __launch_bounds__(64) void k_scan(const float* __restrict__ scan_in, float* __restrict__ y){
  int blk = blockIdx.x;
  int bh = blk>>3, w = blk&7;
  int lane = threadIdx.x;
  int il = lane>>3, c8 = lane&7, jc = c8<<3;
  int i = w*8 + il;
  int b = bh>>3, hh = bh&7;
  const float* base = scan_in + (size_t)bh*Tq*384;
  float* yrow = y + (size_t)b*Tq*Cq + (hh<<6) + i;
  float S[8];
  #pragma unroll
  for (int u=0;u<8;u++) S[u]=0.f;
  Step A_, B_;
  load_step(base, jc, i, A_);
  for (int t=0;t<Tq;t+=2){
    load_step(base + (size_t)(t+1)*384, jc, i, B_);
    float o = step_compute(S, A_);
    if (c8==0) yrow[(size_t)t*Cq] = o;
    if (t+2<Tq) load_step(base + (size_t)(t+2)*384, jc, i, A_);
    o = step_compute(S, B_);
    if (c8==0) yrow[(size_t)(t+1)*Cq] = o;
  }
}

// post-scan: groupnorm + bonus + gate -> split bf16
__global__ __launch_bounds__(512) void k_post(const float* __restrict__ y,
    const float* __restrict__ rb, const float* __restrict__ k2b,
    const float* __restrict__ vb, const float* __restrict__ gb,
    const float* __restrict__ gnw, const float* __restrict__ gnb,
    const float* __restrict__ rk, bf16* __restrict__ zh, bf16* __restrict__ zl){
  int bt = blockIdx.x, c = threadIdx.x;
  size_t ic = (size_t)bt*Cq + c;
  float yv = y[ic];
  float s = yv, q = yv*yv;
  float rr = rb[ic]*k2b[ic]*rk[c];
  #pragma unroll
  for (int m=1;m<64;m<<=1){ s += __shfl_xor(s,m); q += __shfl_xor(q,m); rr += __shfl_xor(rr,m); }
  float mean = s*(1.0f/64.0f);
  float inv = rsqrtf(q*(1.0f/64.0f) - mean*mean + 64e-5f);
  float gn = (yv-mean)*inv*gnw[c] + gnb[c];
  float z = (gn + rr*vb[ic]) * gb[ic];
  bf16 hv = __float2bfloat16(z);
  zh[ic] = hv;
  zl[ic] = __float2bfloat16(z - __bfloat162float(hv));
}

extern "C" void kernel_launch(void* const* d_in, const int* in_sizes, int n_in,
                              void* d_out, int out_size, void* d_ws, size_t ws_size,
                              hipStream_t stream){
  const int*   tok  = (const int*)d_in[0];
  const float* emb  = (const float*)d_in[1];
  const float* ln1w = (const float*)d_in[2];
  const float* ln1b = (const float*)d_in[3];
  const float* mxr  = (const float*)d_in[4];
  const float* mxw  = (const float*)d_in[5];
  const float* mxk  = (const float*)d_in[6];
  const float* mxv  = (const float*)d_in[7];
  const float* mxa  = (const float*)d_in[8];
  const float* mxg  = (const float*)d_in[9];
  const float* w0   = (const float*)d_in[10];
  const float* w1   = (const float*)d_in[11];
  const float* w2   = (const float*)d_in[12];
  const float* a0   = (const float*)d_in[13];
  const float* a1   = (const float*)d_in[14];
  const float* a2   = (const float*)d_in[15];
  const float* v0   = (const float*)d_in[16];
  const float* v1   = (const float*)d_in[17];
  const float* v2   = (const float*)d_in[18];
  const float* g1   = (const float*)d_in[19];
  const float* g2   = (const float*)d_in[20];
  const float* kkw  = (const float*)d_in[21];
  const float* kaw  = (const float*)d_in[22];
  const float* rkw  = (const float*)d_in[23];
  const float* Wr   = (const float*)d_in[24];
  const float* Wk   = (const float*)d_in[25];
  const float* Wv   = (const float*)d_in[26];
  const float* Wo   = (const float*)d_in[27];
  const float* gnw  = (const float*)d_in[28];
  const float* gnb  = (const float*)d_in[29];
  const float* ln2w = (const float*)d_in[30];
  const float* ln2b = (const float*)d_in[31];
  const float* Wfk  = (const float*)d_in[32];
  const float* Wfv  = (const float*)d_in[33];
  const float* lnow = (const float*)d_in[34];
  const float* lnob = (const float*)d_in[35];
  const float* Whead= (const float*)d_in[36];
  const float* bhead= (const float*)d_in[37];
  float* out = (float*)d_out;

  float* ws = (float*)d_ws;
  size_t off = 0;
  const size_t BTC = (size_t)BTq*Cq;
  float* x      = ws + off; off += BTC;
  float* hf     = ws + off; off += BTC;
  float* rb     = ws + off; off += BTC;
  float* kb     = ws + off; off += BTC;
  float* vraw   = ws + off; off += BTC;
  float* vfirst = ws + off; off += BTC;
  float* wpp    = ws + off; off += BTC;
  float* aap    = ws + off; off += BTC;
  float* vvp    = ws + off; off += BTC;
  float* gbuf   = ws + off; off += BTC;
  float* k2b    = ws + off; off += BTC;
  float* vbuf   = ws + off; off += BTC;
  float* yb     = ws + off; off += BTC;
  float* scan_in= ws + off; off += (size_t)Bq*Hq*Tq*384;

  bf16* bp = (bf16*)(ws + off);
  size_t bo = 0;
  bf16* xrh = bp + bo; bo += BTC;  bf16* xrl = bp + bo; bo += BTC;
  bf16* xwh = bp + bo; bo += BTC;  bf16* xwl = bp + bo; bo += BTC;
  bf16* xkh = bp + bo; bo += BTC;  bf16* xkl = bp + bo; bo += BTC;
  bf16* xvh = bp + bo; bo += BTC;  bf16* xvl = bp + bo; bo += BTC;
  bf16* xah = bp + bo; bo += BTC;  bf16* xal = bp + bo; bo += BTC;
  bf16* xgh = bp + bo; bo += BTC;  bf16* xgl = bp + bo; bo += BTC;
  bf16* hh  = bp + bo; bo += BTC;  bf16* hl  = bp + bo; bo += BTC;
  bf16* zbh = bp + bo; bo += BTC;  bf16* zbl = bp + bo; bo += BTC;
  bf16* fkh = bp + bo; bo += (size_t)BTq*F4q;
  bf16* fkl = bp + bo; bo += (size_t)BTq*F4q;
  bf16* t1h = bp + bo; bo += (size_t)BTq*64;  bf16* t1l = bp + bo; bo += (size_t)BTq*64;
  bf16* t2h = bp + bo; bo += (size_t)BTq*64;  bf16* t2l = bp + bo; bo += (size_t)BTq*64;
  bf16* t3h = bp + bo; bo += (size_t)BTq*32;  bf16* t3l = bp + bo; bo += (size_t)BTq*32;
  bf16* t4h = bp + bo; bo += (size_t)BTq*128; bf16* t4l = bp + bo; bo += (size_t)BTq*128;
  const size_t CC = (size_t)Cq*Cq;
  bf16* WrTh = bp + bo; bo += Lq*CC;  bf16* WrTl = bp + bo; bo += Lq*CC;
  bf16* WkTh = bp + bo; bo += Lq*CC;  bf16* WkTl = bp + bo; bo += Lq*CC;
  bf16* WvTh = bp + bo; bo += Lq*CC;  bf16* WvTl = bp + bo; bo += Lq*CC;
  bf16* WoTh = bp + bo; bo += Lq*CC;  bf16* WoTl = bp + bo; bo += Lq*CC;
  const size_t C64 = (size_t)Cq*64, C32 = (size_t)Cq*32, C128 = (size_t)Cq*128;
  bf16* w1Th = bp + bo; bo += Lq*C64; bf16* w1Tl = bp + bo; bo += Lq*C64;
  bf16* w2Th = bp + bo; bo += Lq*C64; bf16* w2Tl = bp + bo; bo += Lq*C64;
  bf16* a1Th = bp + bo; bo += Lq*C64; bf16* a1Tl = bp + bo; bo += Lq*C64;
  bf16* a2Th = bp + bo; bo += Lq*C64; bf16* a2Tl = bp + bo; bo += Lq*C64;
  bf16* v1Th = bp + bo; bo += Lq*C32; bf16* v1Tl = bp + bo; bo += Lq*C32;
  bf16* v2Th = bp + bo; bo += Lq*C32; bf16* v2Tl = bp + bo; bo += Lq*C32;
  bf16* g1Th = bp + bo; bo += Lq*C128; bf16* g1Tl = bp + bo; bo += Lq*C128;
  bf16* g2Th = bp + bo; bo += Lq*C128; bf16* g2Tl = bp + bo; bo += Lq*C128;
  const size_t CF = (size_t)Cq*F4q;
  bf16* WfkTh = bp + bo; bo += CF;  bf16* WfkTl = bp + bo; bo += CF;   // per-layer staged
  bf16* WfvTh = bp + bo; bo += CF;  bf16* WfvTl = bp + bo; bo += CF;
  bf16* WhT   = bp + bo; bo += (size_t)Cq*Vq;

  dim3 tb(32,8);
  k_tr_split<<<dim3(16,16,Lq),tb,0,stream>>>(Wr, WrTh, WrTl, Cq, Cq, CC, CC);
  k_tr_split<<<dim3(16,16,Lq),tb,0,stream>>>(Wk, WkTh, WkTl, Cq, Cq, CC, CC);
  k_tr_split<<<dim3(16,16,Lq),tb,0,stream>>>(Wv, WvTh, WvTl, Cq, Cq, CC, CC);
  k_tr_split<<<dim3(16,16,Lq),tb,0,stream>>>(Wo, WoTh, WoTl, Cq, Cq, CC, CC);
  k_tr_split<<<dim3(2,16,Lq),tb,0,stream>>>(w1, w1Th, w1Tl, Cq, 64, C64, C64);
  k_tr_split<<<dim3(16,2,Lq),tb,0,stream>>>(w2, w2Th, w2Tl, 64, Cq, C64, C64);
  k_tr_split<<<dim3(2,16,Lq),tb,0,stream>>>(a1, a1Th, a1Tl, Cq, 64, C64, C64);
  k_tr_split<<<dim3(16,2,Lq),tb,0,stream>>>(a2, a2Th, a2Tl, 64, Cq, C64, C64);
  k_tr_split<<<dim3(1,16,Lq),tb,0,stream>>>(v1, v1Th, v1Tl, Cq, 32, C32, C32);
  k_tr_split<<<dim3(16,1,Lq),tb,0,stream>>>(v2, v2Th, v2Tl, 32, Cq, C32, C32);
  k_tr_split<<<dim3(4,16,Lq),tb,0,stream>>>(g1, g1Th, g1Tl, Cq, 128, C128, C128);
  k_tr_split<<<dim3(16,4,Lq),tb,0,stream>>>(g2, g2Th, g2Tl, 128, Cq, C128, C128);
  k_tr<<<dim3(80,16,1),tb,0,stream>>>(Whead, WhT, Cq, Vq, 0, 0);

  k_embed<<<BTq,128,0,stream>>>(tok, emb, x);

  dim3 gC(Cq/64, BTq/64);
  dim3 g64(1, BTq/64);
  dim3 g32(1, BTq/64);
  dim3 g128(2, BTq/64);
  dim3 gF(F4q/64, BTq/64);
  dim3 gH(Vq/64, BTq/64);

  for (int l=0;l<Lq;l++){
    size_t lc = (size_t)l*Cq;
    k_ln<<<BTq,128,0,stream>>>(x, ln1w+lc, ln1b+lc, hf);
    k_mix_split<<<BTq,128,0,stream>>>(hf, mxr+lc, mxw+lc, mxk+lc, mxv+lc, mxa+lc, mxg+lc,
                                      xrh,xrl, xwh,xwl, xkh,xkl, xvh,xvl, xah,xal, xgh,xgl);
    k_sgemm<64,64,64,0,0><<<gC,256,0,stream>>>(xrh, xrl, WrTh+l*CC, WrTl+l*CC, rb, nullptr, Cq, Cq);
    k_sgemm<64,64,64,0,0><<<gC,256,0,stream>>>(xkh, xkl, WkTh+l*CC, WkTl+l*CC, kb, nullptr, Cq, Cq);
    k_sgemm<64,64,64,0,0><<<gC,256,0,stream>>>(xvh, xvl, WvTh+l*CC, WvTl+l*CC,
                                               (l==0 ? vfirst : vraw), nullptr, Cq, Cq);
    k_sgemm<64,64,64,1,2><<<g64,256,0,stream>>>(xwh, xwl, w1Th+l*C64, w1Tl+l*C64, t1h, t1l, 64, Cq);
    k_sgemm<64,64,64,0,0><<<gC,256,0,stream>>>(t1h, t1l, w2Th+l*C64, w2Tl+l*C64, wpp, nullptr, Cq, 64);
    k_sgemm<64,64,64,0,2><<<g64,256,0,stream>>>(xah, xal, a1Th+l*C64, a1Tl+l*C64, t2h, t2l, 64, Cq);
    k_sgemm<64,64,64,0,0><<<gC,256,0,stream>>>(t2h, t2l, a2Th+l*C64, a2Tl+l*C64, aap, nullptr, Cq, 64);
    if (l > 0){
      k_sgemm<64,32,64,0,2><<<g32,256,0,stream>>>(xvh, xvl, v1Th+l*C32, v1Tl+l*C32, t3h, t3l, 32, Cq);
      k_sgemm<64,64,32,0,0><<<gC,256,0,stream>>>(t3h, t3l, v2Th+l*C32, v2Tl+l*C32, vvp, nullptr, Cq, 32);
    }
    k_sgemm<64,64,64,2,2><<<g128,256,0,stream>>>(xgh, xgl, g1Th+l*C128, g1Tl+l*C128, t4h, t4l, 128, Cq);
    k_sgemm<64,64,64,0,0><<<gC,256,0,stream>>>(t4h, t4l, g2Th+l*C128, g2Tl+l*C128, gbuf, nullptr, Cq, 128);
    k_prescan<<<dim3(BTq,Hq),64,0,stream>>>(l, rb, kb, vraw, vfirst, wpp, aap, vvp,
                                            w0+lc, a0+lc, v0+lc, kkw+lc, kaw+lc,
                                            scan_in, k2b, vbuf);
    k_scan<<<Bq*Hq*8,64,0,stream>>>(scan_in, yb);
    k_post<<<BTq,512,0,stream>>>(yb, rb, k2b, vbuf, gbuf, gnw+lc, gnb+lc, rkw+lc, zbh, zbl);
    k_sgemm<64,64,64,0,1><<<gC,256,0,stream>>>(zbh, zbl, WoTh+l*CC, WoTl+l*CC, x, nullptr, Cq, Cq);
    k_ln_split<<<BTq,128,0,stream>>>(x, ln2w+lc, ln2b+lc, hh, hl);
    k_tr_split<<<dim3(64,16,1),tb,0,stream>>>(Wfk + l*CF, WfkTh, WfkTl, Cq, F4q, 0, 0);
    k_tr_split<<<dim3(16,64,1),tb,0,stream>>>(Wfv + l*CF, WfvTh, WfvTl, F4q, Cq, 0, 0);
    k_sgemm<64,64,64,3,2><<<gF,256,0,stream>>>(hh, hl, WfkTh, WfkTl, fkh, fkl, F4q, Cq);
    k_sgemm<64,64,64,0,1><<<gC,256,0,stream>>>(fkh, fkl, WfvTh, WfvTl, x, nullptr, Cq, F4q);
  }
  k_ln_bf<<<BTq,128,0,stream>>>(x, lnow, lnob, hh);
  k_mgemm<64,64,64><<<gH,256,0,stream>>>(hh, WhT, bhead, out, Vq, Cq);
}

// Round 7
// 3868.982 us; speedup vs baseline: 2.6420x; 1.1954x over previous
//
#include <hip/hip_runtime.h>
#include <hip/hip_bf16.h>
#include <math.h>

#define Bq 2
#define Tq 512
#define Cq 512
#define Hq 8
#define Lq 12
#define Vq 2560
#define F4q 2048
#define BTq (Bq*Tq)

typedef float4 f4;
typedef __hip_bfloat16 bf16;
typedef __attribute__((ext_vector_type(8))) short bf16x8;
typedef __attribute__((ext_vector_type(4))) float f32x4;

static __device__ __forceinline__ float sigm(float x){ return 1.0f/(1.0f+expf(-x)); }
static __device__ __forceinline__ float splus(float x){ return fmaxf(x,0.0f) + log1pf(expf(-fabsf(x))); }
static __device__ __forceinline__ float b2f(short u){ unsigned int x = ((unsigned int)(unsigned short)u)<<16; float f; __builtin_memcpy(&f,&x,4); return f; }
static __device__ __forceinline__ short f2b(float f){ bf16 h = __float2bfloat16(f); unsigned short us; __builtin_memcpy(&us,&h,2); return (short)us; }

__device__ __forceinline__ void gload16(const void* gptr, void* lptr){
  __builtin_amdgcn_global_load_lds(
    (const __attribute__((address_space(1))) void*)gptr,
    (__attribute__((address_space(3))) void*)lptr, 16, 0, 0);
}

__global__ __launch_bounds__(128) void k_embed(const int* __restrict__ tok,
    const float* __restrict__ emb, float* __restrict__ x){
  int bt = blockIdx.x;
  int id = tok[bt];
  ((f4*)(x + (size_t)bt*Cq))[threadIdx.x] = ((const f4*)(emb + (size_t)id*Cq))[threadIdx.x];
}

// transpose+convert fp32 [K][N] -> bf16 [N][K] (plain, head only)
__global__ __launch_bounds__(256) void k_tr(const float* __restrict__ src, bf16* __restrict__ dst,
    int K, int N, size_t sstride, size_t dstride){
  __shared__ float tile[32][33];
  int l = blockIdx.z;
  const float* s = src + (size_t)l*sstride;
  bf16* d = dst + (size_t)l*dstride;
  int n0 = blockIdx.x*32, k0 = blockIdx.y*32;
  int tx = threadIdx.x, ty = threadIdx.y;
  #pragma unroll
  for (int r=0;r<32;r+=8) tile[ty+r][tx] = s[(size_t)(k0+ty+r)*N + n0+tx];
  __syncthreads();
  #pragma unroll
  for (int r=0;r<32;r+=8) d[(size_t)(n0+ty+r)*K + k0+tx] = __float2bfloat16(tile[tx][ty+r]);
}

// transpose+convert with hi/lo split: fp32 [K][N] -> bf16 [N][K] x2
__global__ __launch_bounds__(256) void k_tr_split(const float* __restrict__ src,
    bf16* __restrict__ dhi, bf16* __restrict__ dlo,
    int K, int N, size_t sstride, size_t dstride){
  __shared__ float tile[32][33];
  int l = blockIdx.z;
  const float* s = src + (size_t)l*sstride;
  int n0 = blockIdx.x*32, k0 = blockIdx.y*32;
  int tx = threadIdx.x, ty = threadIdx.y;
  #pragma unroll
  for (int r=0;r<32;r+=8) tile[ty+r][tx] = s[(size_t)(k0+ty+r)*N + n0+tx];
  __syncthreads();
  #pragma unroll
  for (int r=0;r<32;r+=8){
    float v = tile[tx][ty+r];
    bf16 hv = __float2bfloat16(v);
    size_t idx = (size_t)l*dstride + (size_t)(n0+ty+r)*K + k0+tx;
    dhi[idx] = hv;
    dlo[idx] = __float2bfloat16(v - __bfloat162float(hv));
  }
}

// fused layernorm + time-shift mixes: x fp32 -> six split hi/lo bf16 outputs
__global__ __launch_bounds__(128) void k_lnmix(const float* __restrict__ x,
    const float* __restrict__ lw, const float* __restrict__ lb,
    const float* __restrict__ mr, const float* __restrict__ mw, const float* __restrict__ mk,
    const float* __restrict__ mv, const float* __restrict__ ma, const float* __restrict__ mg,
    bf16* __restrict__ xrh, bf16* __restrict__ xrl,
    bf16* __restrict__ xwh, bf16* __restrict__ xwl,
    bf16* __restrict__ xkh, bf16* __restrict__ xkl,
    bf16* __restrict__ xvh, bf16* __restrict__ xvl,
    bf16* __restrict__ xah, bf16* __restrict__ xal,
    bf16* __restrict__ xgh, bf16* __restrict__ xgl){
  int bt = blockIdx.x, tid = threadIdx.x;
  int t = bt & (Tq-1);
  f4 vc = ((const f4*)(x + (size_t)bt*Cq))[tid];
  f4 vp = make_float4(0.f,0.f,0.f,0.f);
  if (t) vp = ((const f4*)(x + (size_t)(bt-1)*Cq))[tid];
  float sc = vc.x+vc.y+vc.z+vc.w;
  float qc = vc.x*vc.x+vc.y*vc.y+vc.z*vc.z+vc.w*vc.w;
  float sp = vp.x+vp.y+vp.z+vp.w;
  float qp = vp.x*vp.x+vp.y*vp.y+vp.z*vp.z+vp.w*vp.w;
  #pragma unroll
  for (int m=1;m<64;m<<=1){
    sc += __shfl_xor(sc,m); qc += __shfl_xor(qc,m);
    sp += __shfl_xor(sp,m); qp += __shfl_xor(qp,m);
  }
  __shared__ float sh[4][2];
  if ((tid&63)==0){ int w=tid>>6; sh[0][w]=sc; sh[1][w]=qc; sh[2][w]=sp; sh[3][w]=qp; }
  __syncthreads();
  sc = sh[0][0]+sh[0][1]; qc = sh[1][0]+sh[1][1];
  sp = sh[2][0]+sh[2][1]; qp = sh[3][0]+sh[3][1];
  float mc = sc*(1.0f/Cq), ic = rsqrtf(qc*(1.0f/Cq)-mc*mc+1e-5f);
  float mp = sp*(1.0f/Cq), ip = rsqrtf(qp*(1.0f/Cq)-mp*mp+1e-5f);
  f4 W = ((const f4*)lw)[tid], Bb = ((const f4*)lb)[tid];
  float hcx = (vc.x-mc)*ic*W.x+Bb.x, hcy = (vc.y-mc)*ic*W.y+Bb.y;
  float hcz = (vc.z-mc)*ic*W.z+Bb.z, hcw = (vc.w-mc)*ic*W.w+Bb.w;
  float hpx=0.f, hpy=0.f, hpz=0.f, hpw=0.f;
  if (t){
    hpx = (vp.x-mp)*ip*W.x+Bb.x; hpy = (vp.y-mp)*ip*W.y+Bb.y;
    hpz = (vp.z-mp)*ip*W.z+Bb.z; hpw = (vp.w-mp)*ip*W.w+Bb.w;
  }
  float xxx = hpx-hcx, xxy = hpy-hcy, xxz = hpz-hcz, xxw = hpw-hcw;
  #define MIXS(dh, dl, m) { f4 M = ((const f4*)(m))[tid]; \
    float m0 = fmaf(xxx, M.x, hcx), m1 = fmaf(xxy, M.y, hcy); \
    float m2 = fmaf(xxz, M.z, hcz), m3 = fmaf(xxw, M.w, hcw); \
    short4 hi, lo; \
    hi.x = f2b(m0); lo.x = f2b(m0 - b2f(hi.x)); \
    hi.y = f2b(m1); lo.y = f2b(m1 - b2f(hi.y)); \
    hi.z = f2b(m2); lo.z = f2b(m2 - b2f(hi.z)); \
    hi.w = f2b(m3); lo.w = f2b(m3 - b2f(hi.w)); \
    ((short4*)((dh) + (size_t)bt*Cq))[tid] = hi; \
    ((short4*)((dl) + (size_t)bt*Cq))[tid] = lo; }
  MIXS(xrh, xrl, mr) MIXS(xwh, xwl, mw) MIXS(xkh, xkl, mk)
  MIXS(xvh, xvl, mv) MIXS(xah, xal, ma) MIXS(xgh, xgl, mg)
  #undef MIXS
}

// layernorm fp32 -> split bf16 hi/lo
__global__ __launch_bounds__(128) void k_ln_split(const float* __restrict__ x, const float* __restrict__ w,
    const float* __restrict__ b, bf16* __restrict__ oh, bf16* __restrict__ ol){
  int bt = blockIdx.x, tid = threadIdx.x;
  f4 v = ((const f4*)(x + (size_t)bt*Cq))[tid];
  float s = v.x+v.y+v.z+v.w;
  float q = v.x*v.x + v.y*v.y + v.z*v.z + v.w*v.w;
  #pragma unroll
  for (int m=1;m<64;m<<=1){ s += __shfl_xor(s,m); q += __shfl_xor(q,m); }
  __shared__ float ss[2], qs[2];
  if ((tid&63)==0){ ss[tid>>6]=s; qs[tid>>6]=q; }
  __syncthreads();
  s = ss[0]+ss[1]; q = qs[0]+qs[1];
  float mean = s*(1.0f/Cq);
  float inv = rsqrtf(q*(1.0f/Cq) - mean*mean + 1e-5f);
  f4 W = ((const f4*)w)[tid], Bb = ((const f4*)b)[tid];
  float vv[4] = {(v.x-mean)*inv*W.x + Bb.x, (v.y-mean)*inv*W.y + Bb.y,
                 (v.z-mean)*inv*W.z + Bb.z, (v.w-mean)*inv*W.w + Bb.w};
  short4 hi, lo;
  short* hp = &hi.x; short* lp = &lo.x;
  #pragma unroll
  for (int u=0;u<4;u++){ hp[u] = f2b(vv[u]); lp[u] = f2b(vv[u] - b2f(hp[u])); }
  ((short4*)(oh + (size_t)bt*Cq))[tid] = hi;
  ((short4*)(ol + (size_t)bt*Cq))[tid] = lo;
}

// layernorm fp32 -> single bf16 (final, pre-head)
__global__ __launch_bounds__(128) void k_ln_bf(const float* __restrict__ x, const float* __restrict__ w,
    const float* __restrict__ b, bf16* __restrict__ o){
  int bt = blockIdx.x, tid = threadIdx.x;
  f4 v = ((const f4*)(x + (size_t)bt*Cq))[tid];
  float s = v.x+v.y+v.z+v.w;
  float q = v.x*v.x + v.y*v.y + v.z*v.z + v.w*v.w;
  #pragma unroll
  for (int m=1;m<64;m<<=1){ s += __shfl_xor(s,m); q += __shfl_xor(q,m); }
  __shared__ float ss[2], qs[2];
  if ((tid&63)==0){ ss[tid>>6]=s; qs[tid>>6]=q; }
  __syncthreads();
  s = ss[0]+ss[1]; q = qs[0]+qs[1];
  float mean = s*(1.0f/Cq);
  float inv = rsqrtf(q*(1.0f/Cq) - mean*mean + 1e-5f);
  f4 W = ((const f4*)w)[tid], Bb = ((const f4*)b)[tid];
  short4 r;
  r.x = f2b((v.x-mean)*inv*W.x + Bb.x);
  r.y = f2b((v.y-mean)*inv*W.y + Bb.y);
  r.z = f2b((v.z-mean)*inv*W.z + Bb.z);
  r.w = f2b((v.w-mean)*inv*W.w + Bb.w);
  ((short4*)(o + (size_t)bt*Cq))[tid] = r;
}

// ---------------- split-bf16 3-term MFMA GEMM (single shape) ----------------
// OM: 0=fp32 store, 1=fp32 accum, 2=split bf16
template<int BM,int BN,int BK,int ACT,int OM>
__global__ __launch_bounds__(256) void k_sgemm(
    const bf16* __restrict__ Ah, const bf16* __restrict__ Al,
    const bf16* __restrict__ Bh, const bf16* __restrict__ Bl,
    void* __restrict__ Chv, bf16* __restrict__ Cl, int N, int K){
  constexpr int SWZ = (BK==64)?7:3;
  constexpr int ABYTES = BM*BK*2, BBYTES = BN*BK*2;
  __shared__ __align__(16) char lds[2][2*(ABYTES+BBYTES)];
  const int tid = threadIdx.x;
  const int w = tid>>6, ln = tid&63;
  const int wr = w>>1, wc = w&1;
  constexpr int WM = BM/2, WN = BN/2;
  constexpr int MR = WM/16, NR = WN/16;
  const int row0 = blockIdx.y*BM, col0 = blockIdx.x*BN;
  constexpr int LPR = BK/8;
  constexpr int RPC = 64/LPR;
  constexpr int CHA = BM/RPC, CHB = BN/RPC;
  const int srow = ln/LPR;
  const int kb  = (ln%LPR)*16;

  f32x4 acc[MR][NR];
  #pragma unroll
  for (int m=0;m<MR;m++)
    #pragma unroll
    for (int n=0;n<NR;n++)
      acc[m][n] = (f32x4){0.f,0.f,0.f,0.f};

  auto stage = [&](int buf, int k0){
    #pragma unroll
    for (int q=0;q<CHA/4;q++){
      int ch = w*(CHA/4)+q;
      int row = ch*RPC + srow;
      int kbs = kb ^ ((row&SWZ)<<4);
      size_t go = (size_t)(row0+row)*K + k0;
      gload16((const char*)(Ah+go)+kbs, &lds[buf][ch*1024]);
      gload16((const char*)(Al+go)+kbs, &lds[buf][ABYTES + ch*1024]);
    }
    #pragma unroll
    for (int q=0;q<CHB/4;q++){
      int ch = w*(CHB/4)+q;
      int row = ch*RPC + srow;
      int kbs = kb ^ ((row&SWZ)<<4);
      size_t go = (size_t)(col0+row)*K + k0;
      gload16((const char*)(Bh+go)+kbs, &lds[buf][2*ABYTES + ch*1024]);
      gload16((const char*)(Bl+go)+kbs, &lds[buf][2*ABYTES+BBYTES + ch*1024]);
    }
  };

  stage(0, 0);
  __syncthreads();
  const int nt = K/BK;
  for (int t=0;t<nt;t++){
    int buf = t&1;
    if (t+1<nt) stage(buf^1, (t+1)*BK);
    const char* Lah = &lds[buf][0];
    const char* Lal = &lds[buf][ABYTES];
    const char* Lbh = &lds[buf][2*ABYTES];
    const char* Lbl = &lds[buf][2*ABYTES+BBYTES];
    #pragma unroll
    for (int kk=0;kk<BK/32;kk++){
      bf16x8 ah[MR], al[MR], bh[NR], bl[NR];
      int klo = kk*64 + ((ln>>4)<<4);
      #pragma unroll
      for (int m=0;m<MR;m++){
        int row = wr*WM + m*16 + (ln&15);
        int off = row*(BK*2) + (klo ^ ((row&SWZ)<<4));
        ah[m] = *(const bf16x8*)(Lah + off);
        al[m] = *(const bf16x8*)(Lal + off);
      }
      #pragma unroll
      for (int n=0;n<NR;n++){
        int row = wc*WN + n*16 + (ln&15);
        int off = row*(BK*2) + (klo ^ ((row&SWZ)<<4));
        bh[n] = *(const bf16x8*)(Lbh + off);
        bl[n] = *(const bf16x8*)(Lbl + off);
      }
      #pragma unroll
      for (int m=0;m<MR;m++)
        #pragma unroll
        for (int n=0;n<NR;n++){
          acc[m][n] = __builtin_amdgcn_mfma_f32_16x16x32_bf16(ah[m], bh[n], acc[m][n], 0,0,0);
          acc[m][n] = __builtin_amdgcn_mfma_f32_16x16x32_bf16(ah[m], bl[n], acc[m][n], 0,0,0);
          acc[m][n] = __builtin_amdgcn_mfma_f32_16x16x32_bf16(al[m], bh[n], acc[m][n], 0,0,0);
        }
    }
    __syncthreads();
  }

  #pragma unroll
  for (int m=0;m<MR;m++){
    #pragma unroll
    for (int n=0;n<NR;n++){
      int col = col0 + wc*WN + n*16 + (ln&15);
      int rbase = row0 + wr*WM + m*16 + ((ln>>4)<<2);
      #pragma unroll
      for (int r=0;r<4;r++){
        float v = acc[m][n][r];
        if (ACT==1) v = tanhf(v);
        else if (ACT==2) v = sigm(v);
        else if (ACT==3){ v = fmaxf(v,0.f); v = v*v; }
        size_t o = (size_t)(rbase+r)*N + col;
        if (OM==0) ((float*)Chv)[o] = v;
        else if (OM==1) ((float*)Chv)[o] += v;
        else {
          bf16 hv = __float2bfloat16(v);
          ((bf16*)Chv)[o] = hv;
          Cl[o] = __float2bfloat16(v - __bfloat162float(hv));
        }
      }
    }
  }
}

// ---------------- batched variant: per-z pointers + runtime N/K/act ----------------
struct SBatch {
  const bf16* Ah[4]; const bf16* Al[4];
  const bf16* Bh[4]; const bf16* Bl[4];
  void* Ch[4]; bf16* Cl[4];
  int N[4]; int K[4]; int act[4];
};

template<int BM,int BN,int BK,int OM>
__global__ __launch_bounds__(256) void k_sgemm_b(SBatch p){
  const int z = blockIdx.z;
  const int N = p.N[z], K = p.K[z], act = p.act[z];
  const int col0 = blockIdx.x*BN;
  if (col0 >= N) return;
  const bf16* __restrict__ Ah = p.Ah[z];
  const bf16* __restrict__ Al = p.Al[z];
  const bf16* __restrict__ Bh = p.Bh[z];
  const bf16* __restrict__ Bl = p.Bl[z];
  void* Chv = p.Ch[z];
  bf16* Cl = p.Cl[z];
  constexpr int SWZ = (BK==64)?7:3;
  constexpr int ABYTES = BM*BK*2, BBYTES = BN*BK*2;
  __shared__ __align__(16) char lds[2][2*(ABYTES+BBYTES)];
  const int tid = threadIdx.x;
  const int w = tid>>6, ln = tid&63;
  const int wr = w>>1, wc = w&1;
  constexpr int WM = BM/2, WN = BN/2;
  constexpr int MR = WM/16, NR = WN/16;
  const int row0 = blockIdx.y*BM;
  constexpr int LPR = BK/8;
  constexpr int RPC = 64/LPR;
  constexpr int CHA = BM/RPC, CHB = BN/RPC;
  const int srow = ln/LPR;
  const int kb  = (ln%LPR)*16;

  f32x4 acc[MR][NR];
  #pragma unroll
  for (int m=0;m<MR;m++)
    #pragma unroll
    for (int n=0;n<NR;n++)
      acc[m][n] = (f32x4){0.f,0.f,0.f,0.f};

  auto stage = [&](int buf, int k0){
    #pragma unroll
    for (int q=0;q<CHA/4;q++){
      int ch = w*(CHA/4)+q;
      int row = ch*RPC + srow;
      int kbs = kb ^ ((row&SWZ)<<4);
      size_t go = (size_t)(row0+row)*K + k0;
      gload16((const char*)(Ah+go)+kbs, &lds[buf][ch*1024]);
      gload16((const char*)(Al+go)+kbs, &lds[buf][ABYTES + ch*1024]);
    }
    #pragma unroll
    for (int q=0;q<CHB/4;q++){
      int ch = w*(CHB/4)+q;
      int row = ch*RPC + srow;
      int kbs = kb ^ ((row&SWZ)<<4);
      size_t go = (size_t)(col0+row)*K + k0;
      gload16((const char*)(Bh+go)+kbs, &lds[buf][2*ABYTES + ch*1024]);
      gload16((const char*)(Bl+go)+kbs, &lds[buf][2*ABYTES+BBYTES + ch*1024]);
    }
  };

  stage(0, 0);
  __syncthreads();
  const int nt = K/BK;
  for (int t=0;t<nt;t++){
    int buf = t&1;
    if (t+1<nt) stage(buf^1, (t+1)*BK);
    const char* Lah = &lds[buf][0];
    const char* Lal = &lds[buf][ABYTES];
    const char* Lbh = &lds[buf][2*ABYTES];
    const char* Lbl = &lds[buf][2*ABYTES+BBYTES];
    #pragma unroll
    for (int kk=0;kk<BK/32;kk++){
      bf16x8 ah[MR], al[MR], bh[NR], bl[NR];
      int klo = kk*64 + ((ln>>4)<<4);
      #pragma unroll
      for (int m=0;m<MR;m++){
        int row = wr*WM + m*16 + (ln&15);
        int off = row*(BK*2) + (klo ^ ((row&SWZ)<<4));
        ah[m] = *(const bf16x8*)(Lah + off);
        al[m] = *(const bf16x8*)(Lal + off);
      }
      #pragma unroll
      for (int n=0;n<NR;n++){
        int row = wc*WN + n*16 + (ln&15);
        int off = row*(BK*2) + (klo ^ ((row&SWZ)<<4));
        bh[n] = *(const bf16x8*)(Lbh + off);
        bl[n] = *(const bf16x8*)(Lbl + off);
      }
      #pragma unroll
      for (int m=0;m<MR;m++)
        #pragma unroll
        for (int n=0;n<NR;n++){
          acc[m][n] = __builtin_amdgcn_mfma_f32_16x16x32_bf16(ah[m], bh[n], acc[m][n], 0,0,0);
          acc[m][n] = __builtin_amdgcn_mfma_f32_16x16x32_bf16(ah[m], bl[n], acc[m][n], 0,0,0);
          acc[m][n] = __builtin_amdgcn_mfma_f32_16x16x32_bf16(al[m], bh[n], acc[m][n], 0,0,0);
        }
    }
    __syncthreads();
  }

  #pragma unroll
  for (int m=0;m<MR;m++){
    #pragma unroll
    for (int n=0;n<NR;n++){
      int col = col0 + wc*WN + n*16 + (ln&15);
      if (col >= N) continue;
      int rbase = row0 + wr*WM + m*16 + ((ln>>4)<<2);
      #pragma unroll
      for (int r=0;r<4;r++){
        float v = acc[m][n][r];
        if (act==1) v = tanhf(v);
        else if (act==2) v = sigm(v);
        else if (act==3){ v = fmaxf(v,0.f); v = v*v; }
        size_t o = (size_t)(rbase+r)*N + col;
        if (OM==0) ((float*)Chv)[o] = v;
        else if (OM==1) ((float*)Chv)[o] += v;
        else {
          bf16 hv = __float2bfloat16(v);
          ((bf16*)Chv)[o] = hv;
          Cl[o] = __float2bfloat16(v - __bfloat162float(hv));
        }
      }
    }
  }
}

// plain bf16 MFMA GEMM (head only)
template<int BM,int BN,int BK>
__global__ __launch_bounds__(256) void k_mgemm(const bf16* __restrict__ A,
    const bf16* __restrict__ Bt, const float* __restrict__ bias,
    float* __restrict__ Cm, int N, int K){
  constexpr int SWZ = (BK==64)?7:3;
  constexpr int ABYTES = BM*BK*2, BBYTES = BN*BK*2;
  __shared__ __align__(16) char lds[2][ABYTES+BBYTES];
  const int tid = threadIdx.x;
  const int w = tid>>6, ln = tid&63;
  const int wr = w>>1, wc = w&1;
  constexpr int WM = BM/2, WN = BN/2;
  constexpr int MR = WM/16, NR = WN/16;
  const int row0 = blockIdx.y*BM, col0 = blockIdx.x*BN;
  constexpr int LPR = BK/8;
  constexpr int RPC = 64/LPR;
  constexpr int CHA = BM/RPC, CHB = BN/RPC;
  const int srow = ln/LPR;
  const int kb  = (ln%LPR)*16;

  f32x4 acc[MR][NR];
  #pragma unroll
  for (int m=0;m<MR;m++)
    #pragma unroll
    for (int n=0;n<NR;n++)
      acc[m][n] = (f32x4){0.f,0.f,0.f,0.f};

  auto stage = [&](int buf, int k0){
    #pragma unroll
    for (int q=0;q<CHA/4;q++){
      int ch = w*(CHA/4)+q;
      int row = ch*RPC + srow;
      int kbs = kb ^ ((row&SWZ)<<4);
      gload16((const char*)(A + (size_t)(row0+row)*K + k0) + kbs, &lds[buf][ch*1024]);
    }
    #pragma unroll
    for (int q=0;q<CHB/4;q++){
      int ch = w*(CHB/4)+q;
      int row = ch*RPC + srow;
      int kbs = kb ^ ((row&SWZ)<<4);
      gload16((const char*)(Bt + (size_t)(col0+row)*K + k0) + kbs, &lds[buf][ABYTES + ch*1024]);
    }
  };

  stage(0, 0);
  __syncthreads();
  const int nt = K/BK;
  for (int t=0;t<nt;t++){
    int buf = t&1;
    if (t+1<nt) stage(buf^1, (t+1)*BK);
    const char* La = &lds[buf][0];
    const char* Lb = &lds[buf][ABYTES];
    #pragma unroll
    for (int kk=0;kk<BK/32;kk++){
      bf16x8 af[MR], bfr[NR];
      int klo = kk*64 + ((ln>>4)<<4);
      #pragma unroll
      for (int m=0;m<MR;m++){
        int row = wr*WM + m*16 + (ln&15);
        af[m] = *(const bf16x8*)(La + row*(BK*2) + (klo ^ ((row&SWZ)<<4)));
      }
      #pragma unroll
      for (int n=0;n<NR;n++){
        int row = wc*WN + n*16 + (ln&15);
        bfr[n] = *(const bf16x8*)(Lb + row*(BK*2) + (klo ^ ((row&SWZ)<<4)));
      }
      #pragma unroll
      for (int m=0;m<MR;m++)
        #pragma unroll
        for (int n=0;n<NR;n++)
          acc[m][n] = __builtin_amdgcn_mfma_f32_16x16x32_bf16(af[m], bfr[n], acc[m][n], 0,0,0);
    }
    __syncthreads();
  }

  #pragma unroll
  for (int m=0;m<MR;m++){
    #pragma unroll
    for (int n=0;n<NR;n++){
      int col = col0 + wc*WN + n*16 + (ln&15);
      int rbase = row0 + wr*WM + m*16 + ((ln>>4)<<2);
      #pragma unroll
      for (int r=0;r<4;r++)
        Cm[(size_t)(rbase+r)*N + col] = acc[m][n][r] + bias[col];
    }
  }
}

__global__ __launch_bounds__(64) void k_prescan(int layer,
    const float* __restrict__ rb, const float* __restrict__ kb,
    const float* __restrict__ vraw, const float* __restrict__ vfirst,
    const float* __restrict__ wpp, const float* __restrict__ aap, const float* __restrict__ vvp,
    const float* __restrict__ w0, const float* __restrict__ a0, const float* __restrict__ v0,
    const float* __restrict__ kkw, const float* __restrict__ kaw,
    float* __restrict__ scan_in, float* __restrict__ k2b, float* __restrict__ vb){
  int bt = blockIdx.x, hh = blockIdx.y, n = threadIdx.x;
  int c = (hh<<6) + n;
  size_t ic = (size_t)bt*Cq + c;
  int b = bt >> 9, t = bt & (Tq-1);
  float kvv = kb[ic];
  float kkq = kvv * kkw[c];
  float s = kkq*kkq;
  #pragma unroll
  for (int m=1;m<64;m<<=1) s += __shfl_xor(s,m);
  float kkn = kkq / fmaxf(sqrtf(s), 1e-12f);
  float aq = sigm(a0[c] + aap[ic]);
  float wvv = -splus(-(w0[c] + wpp[ic])) - 0.5f;
  float wd = expf(-expf(wvv));
  float vq;
  if (layer==0) vq = vfirst[ic];
  else { float vr = vraw[ic]; vq = fmaf(sigm(v0[c]+vvp[ic]), vfirst[ic]-vr, vr); }
  float k2q = kvv * fmaf(aq-1.0f, kaw[c], 1.0f);
  float* dst = scan_in + ((size_t)(b*Hq+hh)*Tq + t)*384;
  dst[n]       = rb[ic];
  dst[64+n]    = wd;
  dst[128+n]   = k2q;
  dst[192+n]   = vq;
  dst[256+n]   = -kkn;
  dst[320+n]   = kkn*aq;
  k2b[ic] = k2q;
  vb[ic]  = vq;
}

// ---------------- scan: 256 blocks, 4 rows/block, 16 lanes/row, prefetch depth 3 ----------------
struct Step4 { float r[4], w[4], k[4], a[4], b[4], v; };

__device__ __forceinline__ void load_step4(const float* __restrict__ st, int jc, int i, Step4& s){
  *(f4*)&s.r[0] = *(const f4*)(st + jc);
  *(f4*)&s.w[0] = *(const f4*)(st + 64 + jc);
  *(f4*)&s.k[0] = *(const f4*)(st + 128 + jc);
  *(f4*)&s.a[0] = *(const f4*)(st + 256 + jc);
  *(f4*)&s.b[0] = *(const f4*)(st + 320 + jc);
  s.v = st[192 + i];
}

__device__ __forceinline__ float step_compute4(float S[4], const Step4& s){
  float sa = 0.f;
  #pragma unroll
  for (int u=0;u<4;u++) sa = fmaf(S[u], s.a[u], sa);
  sa += __shfl_xor(sa,1); sa += __shfl_xor(sa,2);
  sa += __shfl_xor(sa,4); sa += __shfl_xor(sa,8);
  #pragma unroll
  for (int u=0;u<4;u++)
    S[u] = fmaf(s.v, s.k[u], fmaf(sa, s.b[u], S[u]*s.w[u]));
  float o = 0.f;
  #pragma unroll
  for (int u=0;u<4;u++) o = fmaf(S[u], s.r[u], o);
  o += __shfl_xor(o,1); o += __shfl_xor(o,2);
  o += __shfl_xor(o,4); o += __shfl_xor(o,8);
  return o;
}

__global__ __launch_bounds__(64) void k_scan(const float* __restrict__ scan_in, float* __restrict__ y){
  int blk = blockIdx.x;
  int bh = blk>>4, w = blk&15;
  int lane = threadIdx.x;
  int il = lane>>4, c16 = lane&15, jc = c16<<2;
  int i = w*4 + il;
  int b = bh>>3, hh = bh&7;
  const float* base = scan_in + (size_t)bh*Tq*384;
  float* yrow = y + (size_t)b*Tq*Cq + (hh<<6) + i;
  float S[4] = {0.f,0.f,0.f,0.f};
  Step4 P0,P1,P2,P3;
  load_step4(base,      jc,i,P0);
  load_step4(base+384,  jc,i,P1);
  load_step4(base+768,  jc,i,P2);
  for (int t=0;t<Tq;t+=4){
    if (t+3<Tq) load_step4(base+(size_t)(t+3)*384, jc,i,P3);
    float o = step_compute4(S,P0);
    if (c16==0) yrow[(size_t)t*Cq] = o;
    if (t+4<Tq) load_step4(base+(size_t)(t+4)*384, jc,i,P0);
    o = step_compute4(S,P1);
    if (c16==0) yrow[(size_t)(t+1)*Cq] = o;
    if (t+5<Tq) load_step4(base+(size_t)(t+5)*384, jc,i,P1);
    o = step_compute4(S,P2);
    if (c16==0) yrow[(size_t)(t+2)*Cq] = o;
    if (t+6<Tq) load_step4(base+(size_t)(t+6)*384, jc,i,P2);
    o = step_compute4(S,P3);
    if (c16==0) yrow[(size_t)(t+3)*Cq] = o;
  }
}

// post-scan: groupnorm + bonus + gate -> split bf16
__global__ __launch_bounds__(512) void k_post(const float* __restrict__ y,
    const float* __restrict__ rb, const float* __restrict__ k2b,
    const float* __restrict__ vb, const float* __restrict__ gb,
    const float* __restrict__ gnw, const float* __restrict__ gnb,
    const float* __restrict__ rk, bf16* __restrict__ zh, bf16* __restrict__ zl){
  int bt = blockIdx.x, c = threadIdx.x;
  size_t ic = (size_t)bt*Cq + c;
  float yv = y[ic];
  float s = yv, q = yv*yv;
  float rr = rb[ic]*k2b[ic]*rk[c];
  #pragma unroll
  for (int m=1;m<64;m<<=1){ s += __shfl_xor(s,m); q += __shfl_xor(q,m); rr += __shfl_xor(rr,m); }
  float mean = s*(1.0f/64.0f);
  float inv = rsqrtf(q*(1.0f/64.0f) - mean*mean + 64e-5f);
  float gn = (yv-mean)*inv*gnw[c] + gnb[c];
  float z = (gn + rr*vb[ic]) * gb[ic];
  bf16 hv = __float2bfloat16(z);
  zh[ic] = hv;
  zl[ic] = __float2bfloat16(z - __bfloat162float(hv));
}

extern "C" void kernel_launch(void* const* d_in, const int* in_sizes, int n_in,
                              void* d_out, int out_size, void* d_ws, size_t ws_size,
                              hipStream_t stream){
  const int*   tok  = (const int*)d_in[0];
  const float* emb  = (const float*)d_in[1];
  const float* ln1w = (const float*)d_in[2];
  const float* ln1b = (const float*)d_in[3];
  const float* mxr  = (const float*)d_in[4];
  const float* mxw  = (const float*)d_in[5];
  const float* mxk  = (const float*)d_in[6];
  const float* mxv  = (const float*)d_in[7];
  const float* mxa  = (const float*)d_in[8];
  const float* mxg  = (const float*)d_in[9];
  const float* w0   = (const float*)d_in[10];
  const float* w1   = (const float*)d_in[11];
  const float* w2   = (const float*)d_in[12];
  const float* a0   = (const float*)d_in[13];
  const float* a1   = (const float*)d_in[14];
  const float* a2   = (const float*)d_in[15];
  const float* v0   = (const float*)d_in[16];
  const float* v1   = (const float*)d_in[17];
  const float* v2   = (const float*)d_in[18];
  const float* g1   = (const float*)d_in[19];
  const float* g2   = (const float*)d_in[20];
  const float* kkw  = (const float*)d_in[21];
  const float* kaw  = (const float*)d_in[22];
  const float* rkw  = (const float*)d_in[23];
  const float* Wr   = (const float*)d_in[24];
  const float* Wk   = (const float*)d_in[25];
  const float* Wv   = (const float*)d_in[26];
  const float* Wo   = (const float*)d_in[27];
  const float* gnw  = (const float*)d_in[28];
  const float* gnb  = (const float*)d_in[29];
  const float* ln2w = (const float*)d_in[30];
  const float* ln2b = (const float*)d_in[31];
  const float* Wfk  = (const float*)d_in[32];
  const float* Wfv  = (const float*)d_in[33];
  const float* lnow = (const float*)d_in[34];
  const float* lnob = (const float*)d_in[35];
  const float* Whead= (const float*)d_in[36];
  const float* bhead= (const float*)d_in[37];
  float* out = (float*)d_out;

  float* ws = (float*)d_ws;
  size_t off = 0;
  const size_t BTC = (size_t)BTq*Cq;
  float* x      = ws + off; off += BTC;
  float* rb     = ws + off; off += BTC;
  float* kb     = ws + off; off += BTC;
  float* vraw   = ws + off; off += BTC;
  float* vfirst = ws + off; off += BTC;
  float* wpp    = ws + off; off += BTC;
  float* aap    = ws + off; off += BTC;
  float* vvp    = ws + off; off += BTC;
  float* gbuf   = ws + off; off += BTC;
  float* k2b    = ws + off; off += BTC;
  float* vbuf   = ws + off; off += BTC;
  float* yb     = ws + off; off += BTC;
  float* scan_in= ws + off; off += (size_t)Bq*Hq*Tq*384;

  bf16* bp = (bf16*)(ws + off);
  size_t bo = 0;
  bf16* xrh = bp + bo; bo += BTC;  bf16* xrl = bp + bo; bo += BTC;
  bf16* xwh = bp + bo; bo += BTC;  bf16* xwl = bp + bo; bo += BTC;
  bf16* xkh = bp + bo; bo += BTC;  bf16* xkl = bp + bo; bo += BTC;
  bf16* xvh = bp + bo; bo += BTC;  bf16* xvl = bp + bo; bo += BTC;
  bf16* xah = bp + bo; bo += BTC;  bf16* xal = bp + bo; bo += BTC;
  bf16* xgh = bp + bo; bo += BTC;  bf16* xgl = bp + bo; bo += BTC;
  bf16* hh  = bp + bo; bo += BTC;  bf16* hl  = bp + bo; bo += BTC;
  bf16* zbh = bp + bo; bo += BTC;  bf16* zbl = bp + bo; bo += BTC;
  bf16* fkh = bp + bo; bo += (size_t)BTq*F4q;
  bf16* fkl = bp + bo; bo += (size_t)BTq*F4q;
  bf16* t1h = bp + bo; bo += (size_t)BTq*64;  bf16* t1l = bp + bo; bo += (size_t)BTq*64;
  bf16* t2h = bp + bo; bo += (size_t)BTq*64;  bf16* t2l = bp + bo; bo += (size_t)BTq*64;
  bf16* t3h = bp + bo; bo += (size_t)BTq*32;  bf16* t3l = bp + bo; bo += (size_t)BTq*32;
  bf16* t4h = bp + bo; bo += (size_t)BTq*128; bf16* t4l = bp + bo; bo += (size_t)BTq*128;
  const size_t CC = (size_t)Cq*Cq;
  bf16* WrTh = bp + bo; bo += Lq*CC;  bf16* WrTl = bp + bo; bo += Lq*CC;
  bf16* WkTh = bp + bo; bo += Lq*CC;  bf16* WkTl = bp + bo; bo += Lq*CC;
  bf16* WvTh = bp + bo; bo += Lq*CC;  bf16* WvTl = bp + bo; bo += Lq*CC;
  bf16* WoTh = bp + bo; bo += Lq*CC;  bf16* WoTl = bp + bo; bo += Lq*CC;
  const size_t C64 = (size_t)Cq*64, C32 = (size_t)Cq*32, C128 = (size_t)Cq*128;
  bf16* w1Th = bp + bo; bo += Lq*C64; bf16* w1Tl = bp + bo; bo += Lq*C64;
  bf16* w2Th = bp + bo; bo += Lq*C64; bf16* w2Tl = bp + bo; bo += Lq*C64;
  bf16* a1Th = bp + bo; bo += Lq*C64; bf16* a1Tl = bp + bo; bo += Lq*C64;
  bf16* a2Th = bp + bo; bo += Lq*C64; bf16* a2Tl = bp + bo; bo += Lq*C64;
  bf16* v1Th = bp + bo; bo += Lq*C64; bf16* v1Tl = bp + bo; bo += Lq*C64;  // padded to 64 rows
  bf16* v2Th = bp + bo; bo += Lq*C32; bf16* v2Tl = bp + bo; bo += Lq*C32;
  bf16* g1Th = bp + bo; bo += Lq*C128; bf16* g1Tl = bp + bo; bo += Lq*C128;
  bf16* g2Th = bp + bo; bo += Lq*C128; bf16* g2Tl = bp + bo; bo += Lq*C128;
  const size_t CF = (size_t)Cq*F4q;
  bf16* WfkTh = bp + bo; bo += CF;  bf16* WfkTl = bp + bo; bo += CF;   // per-layer staged
  bf16* WfvTh = bp + bo; bo += CF;  bf16* WfvTl = bp + bo; bo += CF;
  bf16* WhT   = bp + bo; bo += (size_t)Cq*Vq;

  dim3 tb(32,8);
  k_tr_split<<<dim3(16,16,Lq),tb,0,stream>>>(Wr, WrTh, WrTl, Cq, Cq, CC, CC);
  k_tr_split<<<dim3(16,16,Lq),tb,0,stream>>>(Wk, WkTh, WkTl, Cq, Cq, CC, CC);
  k_tr_split<<<dim3(16,16,Lq),tb,0,stream>>>(Wv, WvTh, WvTl, Cq, Cq, CC, CC);
  k_tr_split<<<dim3(16,16,Lq),tb,0,stream>>>(Wo, WoTh, WoTl, Cq, Cq, CC, CC);
  k_tr_split<<<dim3(2,16,Lq),tb,0,stream>>>(w1, w1Th, w1Tl, Cq, 64, C64, C64);
  k_tr_split<<<dim3(16,2,Lq),tb,0,stream>>>(w2, w2Th, w2Tl, 64, Cq, C64, C64);
  k_tr_split<<<dim3(2,16,Lq),tb,0,stream>>>(a1, a1Th, a1Tl, Cq, 64, C64, C64);
  k_tr_split<<<dim3(16,2,Lq),tb,0,stream>>>(a2, a2Th, a2Tl, 64, Cq, C64, C64);
  k_tr_split<<<dim3(1,16,Lq),tb,0,stream>>>(v1, v1Th, v1Tl, Cq, 32, C32, C64);
  k_tr_split<<<dim3(16,1,Lq),tb,0,stream>>>(v2, v2Th, v2Tl, 32, Cq, C32, C32);
  k_tr_split<<<dim3(4,16,Lq),tb,0,stream>>>(g1, g1Th, g1Tl, Cq, 128, C128, C128);
  k_tr_split<<<dim3(16,4,Lq),tb,0,stream>>>(g2, g2Th, g2Tl, 128, Cq, C128, C128);
  k_tr<<<dim3(80,16,1),tb,0,stream>>>(Whead, WhT, Cq, Vq, 0, 0);

  k_embed<<<BTq,128,0,stream>>>(tok, emb, x);

  dim3 gC(Cq/64, BTq/64);
  dim3 gF(F4q/64, BTq/64);
  dim3 gH(Vq/64, BTq/64);

  for (int l=0;l<Lq;l++){
    size_t lc = (size_t)l*Cq;
    k_lnmix<<<BTq,128,0,stream>>>(x, ln1w+lc, ln1b+lc,
                                  mxr+lc, mxw+lc, mxk+lc, mxv+lc, mxa+lc, mxg+lc,
                                  xrh,xrl, xwh,xwl, xkh,xkl, xvh,xvl, xah,xal, xgh,xgl);
    // batched r/k/v (z=3)
    {
      SBatch p{};
      p.Ah[0]=xrh; p.Al[0]=xrl; p.Bh[0]=WrTh+l*CC; p.Bl[0]=WrTl+l*CC; p.Ch[0]=rb;
      p.Ah[1]=xkh; p.Al[1]=xkl; p.Bh[1]=WkTh+l*CC; p.Bl[1]=WkTl+l*CC; p.Ch[1]=kb;
      p.Ah[2]=xvh; p.Al[2]=xvl; p.Bh[2]=WvTh+l*CC; p.Bl[2]=WvTl+l*CC; p.Ch[2]=(l==0?vfirst:vraw);
      for (int z=0;z<3;z++){ p.N[z]=Cq; p.K[z]=Cq; p.act[z]=0; p.Cl[z]=nullptr; }
      k_sgemm_b<64,64,64,0><<<dim3(Cq/64, BTq/64, 3),256,0,stream>>>(p);
    }
    // batched stage-1 projections (z=4): w1(tanh), a1, v1, g1(sigm)
    {
      SBatch p{};
      p.Ah[0]=xwh; p.Al[0]=xwl; p.Bh[0]=w1Th+l*C64;  p.Bl[0]=w1Tl+l*C64;  p.Ch[0]=t1h; p.Cl[0]=t1l; p.N[0]=64;  p.K[0]=Cq; p.act[0]=1;
      p.Ah[1]=xah; p.Al[1]=xal; p.Bh[1]=a1Th+l*C64;  p.Bl[1]=a1Tl+l*C64;  p.Ch[1]=t2h; p.Cl[1]=t2l; p.N[1]=64;  p.K[1]=Cq; p.act[1]=0;
      p.Ah[2]=xvh; p.Al[2]=xvl; p.Bh[2]=v1Th+l*C64;  p.Bl[2]=v1Tl+l*C64;  p.Ch[2]=t3h; p.Cl[2]=t3l; p.N[2]=32;  p.K[2]=Cq; p.act[2]=0;
      p.Ah[3]=xgh; p.Al[3]=xgl; p.Bh[3]=g1Th+l*C128; p.Bl[3]=g1Tl+l*C128; p.Ch[3]=t4h; p.Cl[3]=t4l; p.N[3]=128; p.K[3]=Cq; p.act[3]=2;
      k_sgemm_b<64,64,64,2><<<dim3(2, BTq/64, 4),256,0,stream>>>(p);
    }
    // batched stage-2 projections (z=4): w2, a2, v2, g2 -> fp32
    {
      SBatch p{};
      p.Ah[0]=t1h; p.Al[0]=t1l; p.Bh[0]=w2Th+l*C64;  p.Bl[0]=w2Tl+l*C64;  p.Ch[0]=wpp;  p.N[0]=Cq; p.K[0]=64;  p.act[0]=0;
      p.Ah[1]=t2h; p.Al[1]=t2l; p.Bh[1]=a2Th+l*C64;  p.Bl[1]=a2Tl+l*C64;  p.Ch[1]=aap;  p.N[1]=Cq; p.K[1]=64;  p.act[1]=0;
      p.Ah[2]=t3h; p.Al[2]=t3l; p.Bh[2]=v2Th+l*C32;  p.Bl[2]=v2Tl+l*C32;  p.Ch[2]=vvp;  p.N[2]=Cq; p.K[2]=32;  p.act[2]=0;
      p.Ah[3]=t4h; p.Al[3]=t4l; p.Bh[3]=g2Th+l*C128; p.Bl[3]=g2Tl+l*C128; p.Ch[3]=gbuf; p.N[3]=Cq; p.K[3]=128; p.act[3]=0;
      for (int z=0;z<4;z++) p.Cl[z]=nullptr;
      k_sgemm_b<64,64,32,0><<<dim3(Cq/64, BTq/64, 4),256,0,stream>>>(p);
    }
    k_prescan<<<dim3(BTq,Hq),64,0,stream>>>(l, rb, kb, vraw, vfirst, wpp, aap, vvp,
                                            w0+lc, a0+lc, v0+lc, kkw+lc, kaw+lc,
                                            scan_in, k2b, vbuf);
    k_scan<<<Bq*Hq*16,64,0,stream>>>(scan_in, yb);
    k_post<<<BTq,512,0,stream>>>(yb, rb, k2b, vbuf, gbuf, gnw+lc, gnb+lc, rkw+lc, zbh, zbl);
    k_sgemm<64,64,64,0,1><<<gC,256,0,stream>>>(zbh, zbl, WoTh+l*CC, WoTl+l*CC, x, nullptr, Cq, Cq);
    k_ln_split<<<BTq,128,0,stream>>>(x, ln2w+lc, ln2b+lc, hh, hl);
    k_tr_split<<<dim3(64,16,1),tb,0,stream>>>(Wfk + l*CF, WfkTh, WfkTl, Cq, F4q, 0, 0);
    k_tr_split<<<dim3(16,64,1),tb,0,stream>>>(Wfv + l*CF, WfvTh, WfvTl, F4q, Cq, 0, 0);
    k_sgemm<64,64,64,3,2><<<gF,256,0,stream>>>(hh, hl, WfkTh, WfkTl, fkh, fkl, F4q, Cq);
    k_sgemm<64,64,64,0,1><<<gC,256,0,stream>>>(fkh, fkl, WfvTh, WfvTl, x, nullptr, Cq, F4q);
  }
  k_ln_bf<<<BTq,128,0,stream>>>(x, lnow, lnob, hh);
  k_mgemm<64,64,64><<<gH,256,0,stream>>>(hh, WhT, bhead, out, Vq, Cq);
}